// Round 1
// baseline (1523.214 us; speedup 1.0000x reference)
//
#include <hip/hip_runtime.h>
#include <math.h>

#define N_NODES 50000
#define N_EDGES 1600000
#define DIM 128
#define HEADS 8
#define NEG_SLOPE 0.2f
#define BN_EPS 1e-5f

// ---------------------------------------------------------------------------
// K1: xl = x @ W  (fused: a_src[n,h] = <xl[n,h,:],att_src[h,:]>, same for dst)
// block = 128 threads (one output channel each), NPB nodes per block.
// W column stays in a register across NPB nodes; x rows staged in LDS.
// ---------------------------------------------------------------------------
#define NPB 4
__global__ void k_lin(const float* __restrict__ x, const float* __restrict__ W,
                      const float* __restrict__ att_s, const float* __restrict__ att_d,
                      float* __restrict__ xl, float* __restrict__ a_src,
                      float* __restrict__ a_dst) {
    __shared__ float xs[NPB][DIM];
    const int t = threadIdx.x;
    const int nbase = blockIdx.x * NPB;   // 50000 % NPB == 0, no tail
    #pragma unroll
    for (int i = 0; i < NPB; ++i)
        xs[i][t] = x[(nbase + i) * DIM + t];
    __syncthreads();

    float acc[NPB];
    #pragma unroll
    for (int i = 0; i < NPB; ++i) acc[i] = 0.f;

    #pragma unroll 8
    for (int k = 0; k < DIM; ++k) {
        const float w = W[k * DIM + t];
        #pragma unroll
        for (int i = 0; i < NPB; ++i) acc[i] += xs[i][k] * w;
    }

    const float as = att_s[t];
    const float ad = att_d[t];
    #pragma unroll
    for (int i = 0; i < NPB; ++i) {
        const int n = nbase + i;
        xl[n * DIM + t] = acc[i];
        float s = acc[i] * as;
        float d = acc[i] * ad;
        // reduce over the 16 channels of this head (lanes t&~15 .. |15)
        #pragma unroll
        for (int off = 8; off; off >>= 1) {
            s += __shfl_xor(s, off, 16);
            d += __shfl_xor(d, off, 16);
        }
        if ((t & 15) == 0) {
            a_src[n * HEADS + (t >> 4)] = s;
            a_dst[n * HEADS + (t >> 4)] = d;
        }
    }
}

// ---------------------------------------------------------------------------
// K2: denom[dst,h] += exp(leaky_relu(a_src[src,h] + a_dst[dst,h]))
// One thread per edge; softmax shift skipped (e bounded ~±8, exp safe in fp32,
// softmax is shift-invariant => identical to reference's max-stabilized form).
// ---------------------------------------------------------------------------
__global__ void k_denom(const int* __restrict__ ei, const float* __restrict__ a_src,
                        const float* __restrict__ a_dst, float* __restrict__ denom) {
    const int e = blockIdx.x * blockDim.x + threadIdx.x;
    if (e >= N_EDGES) return;
    const int s = ei[e];
    const int d = ei[N_EDGES + e];
    const float4 s0 = ((const float4*)(a_src + s * HEADS))[0];
    const float4 s1 = ((const float4*)(a_src + s * HEADS))[1];
    const float4 d0 = ((const float4*)(a_dst + d * HEADS))[0];
    const float4 d1 = ((const float4*)(a_dst + d * HEADS))[1];
    float ev[HEADS] = {s0.x + d0.x, s0.y + d0.y, s0.z + d0.z, s0.w + d0.w,
                       s1.x + d1.x, s1.y + d1.y, s1.z + d1.z, s1.w + d1.w};
    float* db = denom + d * HEADS;
    #pragma unroll
    for (int h = 0; h < HEADS; ++h) {
        float v = ev[h];
        v = v > 0.f ? v : NEG_SLOPE * v;
        atomicAdd(db + h, __expf(v));
    }
}

// ---------------------------------------------------------------------------
// K3: out[dst, c] += alpha(e,h) * xl[src, c]   (c = h*16 + cc)
// One thread per (edge, channel); 2 edges per 256-thread block.
// ---------------------------------------------------------------------------
__global__ void k_aggr(const int* __restrict__ ei, const float* __restrict__ a_src,
                       const float* __restrict__ a_dst, const float* __restrict__ denom,
                       const float* __restrict__ xl, float* __restrict__ out) {
    const int gid = blockIdx.x * blockDim.x + threadIdx.x;
    const int e = gid >> 7;
    const int c = gid & (DIM - 1);
    const int s = ei[e];
    const int d = ei[N_EDGES + e];
    const int h = c >> 4;
    float ev = a_src[s * HEADS + h] + a_dst[d * HEADS + h];
    ev = ev > 0.f ? ev : NEG_SLOPE * ev;
    const float alpha = __expf(ev) / (denom[d * HEADS + h] + 1e-16f);
    atomicAdd(out + d * DIM + c, alpha * xl[s * DIM + c]);
}

// ---------------------------------------------------------------------------
// K4: per-channel sums for BatchNorm (h = out + bias)
// ---------------------------------------------------------------------------
__global__ void k_stats(const float* __restrict__ out, const float* __restrict__ bias,
                        float* __restrict__ sums, float* __restrict__ sumsq) {
    const int c = threadIdx.x;
    const float b = bias[c];
    float s = 0.f, ss = 0.f;
    for (int n = blockIdx.x; n < N_NODES; n += gridDim.x) {
        const float h = out[n * DIM + c] + b;
        s += h;
        ss += h * h;
    }
    atomicAdd(sums + c, s);
    atomicAdd(sumsq + c, ss);
}

// K5: fold mean/var/gamma/beta/bias into per-channel scale+shift
__global__ void k_statfin(const float* __restrict__ sums, const float* __restrict__ sumsq,
                          const float* __restrict__ gamma, const float* __restrict__ beta,
                          const float* __restrict__ bias, float* __restrict__ scale,
                          float* __restrict__ shift) {
    const int c = threadIdx.x;
    const float inv_n = 1.f / (float)N_NODES;
    const float mean = sums[c] * inv_n;          // mean of (out + bias)
    const float var = sumsq[c] * inv_n - mean * mean;  // biased variance
    const float sc = rsqrtf(var + BN_EPS) * gamma[c];
    scale[c] = sc;
    // y = relu((out + bias - mean)*sc + beta) + x  =>  relu(out*sc + shift) + x
    shift[c] = beta[c] + (bias[c] - mean) * sc;
}

// K6: y = x + relu(out*scale + shift)
__global__ void k_final(const float* __restrict__ out, const float* __restrict__ x,
                        const float* __restrict__ scale, const float* __restrict__ shift,
                        float* __restrict__ y) {
    const int i = blockIdx.x * blockDim.x + threadIdx.x;
    const int c = i & (DIM - 1);
    const float bn = out[i] * scale[c] + shift[c];
    y[i] = x[i] + fmaxf(bn, 0.f);
}

extern "C" void kernel_launch(void* const* d_in, const int* in_sizes, int n_in,
                              void* d_out, int out_size, void* d_ws, size_t ws_size,
                              hipStream_t stream) {
    const float* x     = (const float*)d_in[0];
    const int*   ei    = (const int*)  d_in[1];   // [2, E] flat: src then dst
    const float* W     = (const float*)d_in[2];
    const float* att_s = (const float*)d_in[3];
    const float* att_d = (const float*)d_in[4];
    const float* bias  = (const float*)d_in[5];
    const float* gamma = (const float*)d_in[6];
    const float* beta  = (const float*)d_in[7];
    float* y = (float*)d_out;

    // workspace layout (floats)
    float* ws    = (float*)d_ws;
    float* out   = ws;                    // 6,400,000
    float* denom = out   + (size_t)N_NODES * DIM;     // 400,000
    float* sums  = denom + (size_t)N_NODES * HEADS;   // 128
    float* sumsq = sums  + DIM;                       // 128
    float* xl    = sumsq + DIM;                       // 6,400,000
    float* a_src = xl    + (size_t)N_NODES * DIM;     // 400,000
    float* a_dst = a_src + (size_t)N_NODES * HEADS;   // 400,000
    float* scale = a_dst + (size_t)N_NODES * HEADS;   // 128
    float* shift = scale + DIM;                       // 128

    // zero the accumulators (out, denom, sums, sumsq are contiguous)
    const size_t zero_floats = (size_t)N_NODES * DIM + (size_t)N_NODES * HEADS + 2 * DIM;
    hipMemsetAsync(out, 0, zero_floats * sizeof(float), stream);

    k_lin<<<N_NODES / NPB, DIM, 0, stream>>>(x, W, att_s, att_d, xl, a_src, a_dst);
    k_denom<<<(N_EDGES + 255) / 256, 256, 0, stream>>>(ei, a_src, a_dst, denom);
    k_aggr<<<(size_t)N_EDGES * DIM / 256, 256, 0, stream>>>(ei, a_src, a_dst, denom, xl, out);
    k_stats<<<512, DIM, 0, stream>>>(out, bias, sums, sumsq);
    k_statfin<<<1, DIM, 0, stream>>>(sums, sumsq, gamma, beta, bias, scale, shift);
    k_final<<<(size_t)N_NODES * DIM / 256, 256, 0, stream>>>(out, x, scale, shift, y);
}

// Round 2
// 516.360 us; speedup vs baseline: 2.9499x; 2.9499x over previous
//
#include <hip/hip_runtime.h>
#include <math.h>

#define N_NODES 50000
#define N_EDGES 1600000
#define DIM 128
#define HEADS 8
#define NEG_SLOPE 0.2f
#define BN_EPS 1e-5f

// ---------------------------------------------------------------------------
// K1: xl = x @ W  (fused: a_src[n,h] = <xl[n,h,:],att_src[h,:]>, same for dst)
// ---------------------------------------------------------------------------
#define NPB 4
__global__ void k_lin(const float* __restrict__ x, const float* __restrict__ W,
                      const float* __restrict__ att_s, const float* __restrict__ att_d,
                      float* __restrict__ xl, float* __restrict__ a_src,
                      float* __restrict__ a_dst) {
    __shared__ float xs[NPB][DIM];
    const int t = threadIdx.x;
    const int nbase = blockIdx.x * NPB;   // 50000 % NPB == 0, no tail
    #pragma unroll
    for (int i = 0; i < NPB; ++i)
        xs[i][t] = x[(nbase + i) * DIM + t];
    __syncthreads();

    float acc[NPB];
    #pragma unroll
    for (int i = 0; i < NPB; ++i) acc[i] = 0.f;

    #pragma unroll 8
    for (int k = 0; k < DIM; ++k) {
        const float w = W[k * DIM + t];
        #pragma unroll
        for (int i = 0; i < NPB; ++i) acc[i] += xs[i][k] * w;
    }

    const float as = att_s[t];
    const float ad = att_d[t];
    #pragma unroll
    for (int i = 0; i < NPB; ++i) {
        const int n = nbase + i;
        xl[n * DIM + t] = acc[i];
        float s = acc[i] * as;
        float d = acc[i] * ad;
        #pragma unroll
        for (int off = 8; off; off >>= 1) {
            s += __shfl_xor(s, off, 16);
            d += __shfl_xor(d, off, 16);
        }
        if ((t & 15) == 0) {
            a_src[n * HEADS + (t >> 4)] = s;
            a_dst[n * HEADS + (t >> 4)] = d;
        }
    }
}

// ---------------------------------------------------------------------------
// CSR build: histogram -> exclusive scan (3 kernels) -> scatter
// ---------------------------------------------------------------------------
__global__ void k_hist(const int* __restrict__ ei, int* __restrict__ deg) {
    const int e = blockIdx.x * blockDim.x + threadIdx.x;
    if (e < N_EDGES) atomicAdd(&deg[ei[N_EDGES + e]], 1);
}

#define SCAN_B 256
#define SCAN_NB ((N_NODES + SCAN_B - 1) / SCAN_B)   // 196

__global__ void k_scanA(const int* __restrict__ deg, int* __restrict__ off,
                        int* __restrict__ bsum) {
    __shared__ int s[SCAN_B];
    const int t = threadIdx.x;
    const int i = blockIdx.x * SCAN_B + t;
    const int v = (i < N_NODES) ? deg[i] : 0;
    s[t] = v;
    __syncthreads();
    for (int d = 1; d < SCAN_B; d <<= 1) {
        const int xo = (t >= d) ? s[t - d] : 0;
        __syncthreads();
        s[t] += xo;
        __syncthreads();
    }
    if (i < N_NODES) off[i] = s[t] - v;              // exclusive prefix
    if (t == SCAN_B - 1) bsum[blockIdx.x] = s[t];    // block total
}

__global__ void k_scanB(int* __restrict__ bsum) {
    __shared__ int s[SCAN_B];
    const int t = threadIdx.x;
    const int v = (t < SCAN_NB) ? bsum[t] : 0;
    s[t] = v;
    __syncthreads();
    for (int d = 1; d < SCAN_B; d <<= 1) {
        const int xo = (t >= d) ? s[t - d] : 0;
        __syncthreads();
        s[t] += xo;
        __syncthreads();
    }
    if (t < SCAN_NB) bsum[t] = s[t] - v;             // exclusive
}

__global__ void k_scanC(int* __restrict__ off, const int* __restrict__ bsum) {
    const int t = threadIdx.x;
    const int i = blockIdx.x * SCAN_B + t;
    if (i < N_NODES) off[i] += bsum[blockIdx.x];
    if (i == 0) off[N_NODES] = N_EDGES;
}

__global__ void k_scatter(const int* __restrict__ ei, const int* __restrict__ off,
                          int* __restrict__ cur, int* __restrict__ csr_src) {
    const int e = blockIdx.x * blockDim.x + threadIdx.x;
    if (e >= N_EDGES) return;
    const int s = ei[e];
    const int d = ei[N_EDGES + e];
    const int pos = off[d] + atomicAdd(&cur[d], 1);
    csr_src[pos] = s;
}

// ---------------------------------------------------------------------------
// K3: fused softmax + aggregation, no atomics.
// One 128-thread block per dst node; thread c owns channel c (head h=c>>4).
// Single pass over incoming edges accumulates numerator AND denominator.
// ---------------------------------------------------------------------------
__global__ void k_aggr2(const int* __restrict__ off, const int* __restrict__ csr_src,
                        const float* __restrict__ a_src, const float* __restrict__ a_dst,
                        const float* __restrict__ xl, float* __restrict__ y) {
    const int d = blockIdx.x;
    const int c = threadIdx.x;
    const int h = c >> 4;
    const int lo = off[d], hi = off[d + 1];
    const float ad = a_dst[d * HEADS + h];
    float acc = 0.f, dsum = 0.f;
    for (int i = lo; i < hi; ++i) {
        const int s = csr_src[i];
        float ev = a_src[s * HEADS + h] + ad;
        ev = ev > 0.f ? ev : NEG_SLOPE * ev;
        const float w = __expf(ev);
        acc += w * xl[s * DIM + c];
        dsum += w;
    }
    y[d * DIM + c] = acc / (dsum + 1e-16f);
}

// ---------------------------------------------------------------------------
// BN stats over h = y + bias
// ---------------------------------------------------------------------------
__global__ void k_stats(const float* __restrict__ y, const float* __restrict__ bias,
                        float* __restrict__ sums, float* __restrict__ sumsq) {
    const int c = threadIdx.x;
    const float b = bias[c];
    float s = 0.f, ss = 0.f;
    for (int n = blockIdx.x; n < N_NODES; n += gridDim.x) {
        const float h = y[n * DIM + c] + b;
        s += h;
        ss += h * h;
    }
    atomicAdd(sums + c, s);
    atomicAdd(sumsq + c, ss);
}

__global__ void k_statfin(const float* __restrict__ sums, const float* __restrict__ sumsq,
                          const float* __restrict__ gamma, const float* __restrict__ beta,
                          const float* __restrict__ bias, float* __restrict__ scale,
                          float* __restrict__ shift) {
    const int c = threadIdx.x;
    const float inv_n = 1.f / (float)N_NODES;
    const float mean = sums[c] * inv_n;
    const float var = sumsq[c] * inv_n - mean * mean;
    const float sc = rsqrtf(var + BN_EPS) * gamma[c];
    scale[c] = sc;
    shift[c] = beta[c] + (bias[c] - mean) * sc;
}

// in-place: y = x + relu(y*scale + shift)
__global__ void k_final(float* __restrict__ y, const float* __restrict__ x,
                        const float* __restrict__ scale, const float* __restrict__ shift) {
    const int i = blockIdx.x * blockDim.x + threadIdx.x;
    const int c = i & (DIM - 1);
    const float bn = y[i] * scale[c] + shift[c];
    y[i] = x[i] + fmaxf(bn, 0.f);
}

extern "C" void kernel_launch(void* const* d_in, const int* in_sizes, int n_in,
                              void* d_out, int out_size, void* d_ws, size_t ws_size,
                              hipStream_t stream) {
    const float* x     = (const float*)d_in[0];
    const int*   ei    = (const int*)  d_in[1];   // [2, E] flat: src row then dst row
    const float* W     = (const float*)d_in[2];
    const float* att_s = (const float*)d_in[3];
    const float* att_d = (const float*)d_in[4];
    const float* bias  = (const float*)d_in[5];
    const float* gamma = (const float*)d_in[6];
    const float* beta  = (const float*)d_in[7];
    float* y = (float*)d_out;

    // workspace layout
    float* ws    = (float*)d_ws;
    float* xl    = ws;                               // 6,400,000 f
    float* a_src = xl    + (size_t)N_NODES * DIM;    // 400,000 f
    float* a_dst = a_src + (size_t)N_NODES * HEADS;  // 400,000 f
    float* sums  = a_dst + (size_t)N_NODES * HEADS;  // 128 f
    float* sumsq = sums  + DIM;                      // 128 f
    float* scale = sumsq + DIM;                      // 128 f
    float* shift = scale + DIM;                      // 128 f
    int*   deg   = (int*)(shift + DIM);              // 50,000 i
    int*   cur   = deg   + N_NODES;                  // 50,000 i
    int*   bsum  = cur   + N_NODES;                  // 256 i
    int*   off   = bsum  + SCAN_B;                   // 50,001 i
    int*   csr   = off   + N_NODES + 1;              // 1,600,000 i

    // zero: sums, sumsq, scale, shift, deg, cur (contiguous)
    hipMemsetAsync(sums, 0, (4 * DIM + 2 * N_NODES) * sizeof(float), stream);

    k_lin<<<N_NODES / NPB, DIM, 0, stream>>>(x, W, att_s, att_d, xl, a_src, a_dst);
    k_hist<<<(N_EDGES + 255) / 256, 256, 0, stream>>>(ei, deg);
    k_scanA<<<SCAN_NB, SCAN_B, 0, stream>>>(deg, off, bsum);
    k_scanB<<<1, SCAN_B, 0, stream>>>(bsum);
    k_scanC<<<SCAN_NB, SCAN_B, 0, stream>>>(off, bsum);
    k_scatter<<<(N_EDGES + 255) / 256, 256, 0, stream>>>(ei, off, cur, csr);
    k_aggr2<<<N_NODES, DIM, 0, stream>>>(off, csr, a_src, a_dst, xl, y);
    k_stats<<<512, DIM, 0, stream>>>(y, bias, sums, sumsq);
    k_statfin<<<1, DIM, 0, stream>>>(sums, sumsq, gamma, beta, bias, scale, shift);
    k_final<<<(size_t)N_NODES * DIM / 256, 256, 0, stream>>>(y, x, scale, shift);
}

// Round 3
// 433.981 us; speedup vs baseline: 3.5099x; 1.1898x over previous
//
#include <hip/hip_runtime.h>
#include <hip/hip_fp16.h>
#include <math.h>

#define N_NODES 50000
#define N_EDGES 1600000
#define DIM 128
#define HEADS 8
#define NEG_SLOPE 0.2f
#define BN_EPS 1e-5f

// ---------------------------------------------------------------------------
// K1: xl = x @ W (xl stored fp16), fused per-head attention dots (fp32).
// No LDS: x reads are thread-uniform -> scalar loads (SMEM pipe); W streams
// through L1 per lane. 8 FMA per W load.
// ---------------------------------------------------------------------------
#define NPB 8
__global__ void k_lin(const float* __restrict__ x, const float* __restrict__ W,
                      const float* __restrict__ att_s, const float* __restrict__ att_d,
                      __half* __restrict__ xlh, float* __restrict__ a_src,
                      float* __restrict__ a_dst) {
    const int t = threadIdx.x;              // output channel 0..127
    const int nbase = blockIdx.x * NPB;     // 50000 % 8 == 0
    float acc[NPB];
    #pragma unroll
    for (int i = 0; i < NPB; ++i) acc[i] = 0.f;
    const float* xr = x + (size_t)nbase * DIM;
    #pragma unroll 4
    for (int k = 0; k < DIM; ++k) {
        const float w = W[k * DIM + t];
        #pragma unroll
        for (int i = 0; i < NPB; ++i)
            acc[i] = fmaf(xr[i * DIM + k], w, acc[i]);   // uniform -> s_load
    }
    const float as = att_s[t];
    const float ad = att_d[t];
    #pragma unroll
    for (int i = 0; i < NPB; ++i) {
        const int n = nbase + i;
        xlh[(size_t)n * DIM + t] = __float2half(acc[i]);
        float s = acc[i] * as;
        float d = acc[i] * ad;
        #pragma unroll
        for (int off = 8; off; off >>= 1) {
            s += __shfl_xor(s, off, 16);
            d += __shfl_xor(d, off, 16);
        }
        if ((t & 15) == 0) {
            a_src[n * HEADS + (t >> 4)] = s;
            a_dst[n * HEADS + (t >> 4)] = d;
        }
    }
}

// ---------------------------------------------------------------------------
// CSR build: histogram -> exclusive scan -> scatter (reverse-fill, no cur[])
// ---------------------------------------------------------------------------
__global__ void k_hist(const int* __restrict__ ei, int* __restrict__ deg) {
    const int e = blockIdx.x * blockDim.x + threadIdx.x;
    if (e < N_EDGES) atomicAdd(&deg[ei[N_EDGES + e]], 1);
}

#define SCAN_B 256
#define SCAN_NB ((N_NODES + SCAN_B - 1) / SCAN_B)   // 196

__global__ void k_scanA(const int* __restrict__ deg, int* __restrict__ off,
                        int* __restrict__ bsum) {
    __shared__ int s[SCAN_B];
    const int t = threadIdx.x;
    const int i = blockIdx.x * SCAN_B + t;
    const int v = (i < N_NODES) ? deg[i] : 0;
    s[t] = v;
    __syncthreads();
    for (int d = 1; d < SCAN_B; d <<= 1) {
        const int xo = (t >= d) ? s[t - d] : 0;
        __syncthreads();
        s[t] += xo;
        __syncthreads();
    }
    if (i < N_NODES) off[i] = s[t] - v;
    if (t == SCAN_B - 1) bsum[blockIdx.x] = s[t];
}

__global__ void k_scanB(int* __restrict__ bsum) {
    __shared__ int s[SCAN_B];
    const int t = threadIdx.x;
    const int v = (t < SCAN_NB) ? bsum[t] : 0;
    s[t] = v;
    __syncthreads();
    for (int d = 1; d < SCAN_B; d <<= 1) {
        const int xo = (t >= d) ? s[t - d] : 0;
        __syncthreads();
        s[t] += xo;
        __syncthreads();
    }
    if (t < SCAN_NB) bsum[t] = s[t] - v;
}

__global__ void k_scanC(int* __restrict__ off, const int* __restrict__ bsum) {
    const int t = threadIdx.x;
    const int i = blockIdx.x * SCAN_B + t;
    if (i < N_NODES) off[i] += bsum[blockIdx.x];
    if (i == 0) off[N_NODES] = N_EDGES;
}

__global__ void k_scatter(const int* __restrict__ ei, const int* __restrict__ off,
                          int* __restrict__ deg, int* __restrict__ csr_src) {
    const int e = blockIdx.x * blockDim.x + threadIdx.x;
    if (e >= N_EDGES) return;
    const int s = ei[e];
    const int d = ei[N_EDGES + e];
    const int pos = off[d] + atomicSub(&deg[d], 1) - 1;  // reverse-fill
    csr_src[pos] = s;
}

// ---------------------------------------------------------------------------
// K3: fused softmax + aggregation. One WAVE per dst node; lane owns 2
// adjacent channels (half2 gather = 1 dword/lane). Edge loop unrolled x4
// for 4 outstanding gathers. No atomics, no LDS.
// ---------------------------------------------------------------------------
__global__ void k_aggr2(const int* __restrict__ off, const int* __restrict__ csr_src,
                        const float* __restrict__ a_src, const float* __restrict__ a_dst,
                        const __half* __restrict__ xlh, float* __restrict__ y) {
    const int d = blockIdx.x * 4 + (threadIdx.x >> 6);
    const int lane = threadIdx.x & 63;
    const int c2 = lane << 1;           // channel pair base
    const int h = lane >> 3;            // head
    const int lo = off[d], hi = off[d + 1];
    const float ad = a_dst[d * HEADS + h];
    float acc0 = 0.f, acc1 = 0.f, dsum = 0.f;
    int i = lo;
    for (; i + 4 <= hi; i += 4) {
        const int s0 = csr_src[i + 0], s1 = csr_src[i + 1];
        const int s2 = csr_src[i + 2], s3 = csr_src[i + 3];
        const float e0 = a_src[s0 * HEADS + h] + ad;
        const float e1 = a_src[s1 * HEADS + h] + ad;
        const float e2 = a_src[s2 * HEADS + h] + ad;
        const float e3 = a_src[s3 * HEADS + h] + ad;
        const __half2 x0 = *(const __half2*)(xlh + (size_t)s0 * DIM + c2);
        const __half2 x1 = *(const __half2*)(xlh + (size_t)s1 * DIM + c2);
        const __half2 x2 = *(const __half2*)(xlh + (size_t)s2 * DIM + c2);
        const __half2 x3 = *(const __half2*)(xlh + (size_t)s3 * DIM + c2);
        const float w0 = __expf(fmaxf(e0, NEG_SLOPE * e0));
        const float w1 = __expf(fmaxf(e1, NEG_SLOPE * e1));
        const float w2 = __expf(fmaxf(e2, NEG_SLOPE * e2));
        const float w3 = __expf(fmaxf(e3, NEG_SLOPE * e3));
        float2 f;
        f = __half22float2(x0); acc0 = fmaf(w0, f.x, acc0); acc1 = fmaf(w0, f.y, acc1);
        f = __half22float2(x1); acc0 = fmaf(w1, f.x, acc0); acc1 = fmaf(w1, f.y, acc1);
        f = __half22float2(x2); acc0 = fmaf(w2, f.x, acc0); acc1 = fmaf(w2, f.y, acc1);
        f = __half22float2(x3); acc0 = fmaf(w3, f.x, acc0); acc1 = fmaf(w3, f.y, acc1);
        dsum += (w0 + w1) + (w2 + w3);
    }
    for (; i < hi; ++i) {
        const int s = csr_src[i];
        const float e = a_src[s * HEADS + h] + ad;
        const __half2 xv = *(const __half2*)(xlh + (size_t)s * DIM + c2);
        const float w = __expf(fmaxf(e, NEG_SLOPE * e));
        const float2 f = __half22float2(xv);
        acc0 = fmaf(w, f.x, acc0); acc1 = fmaf(w, f.y, acc1); dsum += w;
    }
    const float inv = 1.f / (dsum + 1e-16f);
    float2 o; o.x = acc0 * inv; o.y = acc1 * inv;
    *(float2*)(y + (size_t)d * DIM + c2) = o;
}

// ---------------------------------------------------------------------------
// BN stats over h = y + bias
// ---------------------------------------------------------------------------
__global__ void k_stats(const float* __restrict__ y, const float* __restrict__ bias,
                        float* __restrict__ sums, float* __restrict__ sumsq) {
    const int c = threadIdx.x;
    const float b = bias[c];
    float s = 0.f, ss = 0.f;
    for (int n = blockIdx.x; n < N_NODES; n += gridDim.x) {
        const float h = y[n * DIM + c] + b;
        s += h;
        ss += h * h;
    }
    atomicAdd(sums + c, s);
    atomicAdd(sumsq + c, ss);
}

__global__ void k_statfin(const float* __restrict__ sums, const float* __restrict__ sumsq,
                          const float* __restrict__ gamma, const float* __restrict__ beta,
                          const float* __restrict__ bias, float* __restrict__ scale,
                          float* __restrict__ shift) {
    const int c = threadIdx.x;
    const float inv_n = 1.f / (float)N_NODES;
    const float mean = sums[c] * inv_n;
    const float var = sumsq[c] * inv_n - mean * mean;
    const float sc = rsqrtf(var + BN_EPS) * gamma[c];
    scale[c] = sc;
    shift[c] = beta[c] + (bias[c] - mean) * sc;
}

// in-place float4: y = x + relu(y*scale + shift)
__global__ void k_final(float* __restrict__ y, const float* __restrict__ x,
                        const float* __restrict__ scale, const float* __restrict__ shift) {
    const int q = blockIdx.x * blockDim.x + threadIdx.x;  // float4 index
    const int cq = q & (DIM / 4 - 1);
    float4 v = ((const float4*)y)[q];
    const float4 xv = ((const float4*)x)[q];
    const float4 sc = ((const float4*)scale)[cq];
    const float4 sh = ((const float4*)shift)[cq];
    v.x = xv.x + fmaxf(v.x * sc.x + sh.x, 0.f);
    v.y = xv.y + fmaxf(v.y * sc.y + sh.y, 0.f);
    v.z = xv.z + fmaxf(v.z * sc.z + sh.z, 0.f);
    v.w = xv.w + fmaxf(v.w * sc.w + sh.w, 0.f);
    ((float4*)y)[q] = v;
}

extern "C" void kernel_launch(void* const* d_in, const int* in_sizes, int n_in,
                              void* d_out, int out_size, void* d_ws, size_t ws_size,
                              hipStream_t stream) {
    const float* x     = (const float*)d_in[0];
    const int*   ei    = (const int*)  d_in[1];   // [2,E] flat: src row then dst row
    const float* W     = (const float*)d_in[2];
    const float* att_s = (const float*)d_in[3];
    const float* att_d = (const float*)d_in[4];
    const float* bias  = (const float*)d_in[5];
    const float* gamma = (const float*)d_in[6];
    const float* beta  = (const float*)d_in[7];
    float* y = (float*)d_out;

    // workspace layout
    __half* xlh  = (__half*)d_ws;                          // 6,400,000 h (12.8 MB)
    float* a_src = (float*)(xlh + (size_t)N_NODES * DIM);  // 400,000 f
    float* a_dst = a_src + (size_t)N_NODES * HEADS;        // 400,000 f
    float* sums  = a_dst + (size_t)N_NODES * HEADS;        // 128 f
    float* sumsq = sums  + DIM;                            // 128 f
    float* scale = sumsq + DIM;                            // 128 f
    float* shift = scale + DIM;                            // 128 f
    int*   deg   = (int*)(shift + DIM);                    // 50,000 i
    int*   bsum  = deg   + N_NODES;                        // 256 i
    int*   off   = bsum  + SCAN_B;                         // 50,001 i
    int*   csr   = off   + N_NODES + 1;                    // 1,600,000 i

    // zero sums/sumsq/scale/shift + deg (contiguous)
    hipMemsetAsync(sums, 0, (4 * DIM + N_NODES) * sizeof(float), stream);

    k_lin<<<N_NODES / NPB, DIM, 0, stream>>>(x, W, att_s, att_d, xlh, a_src, a_dst);
    k_hist<<<(N_EDGES + 255) / 256, 256, 0, stream>>>(ei, deg);
    k_scanA<<<SCAN_NB, SCAN_B, 0, stream>>>(deg, off, bsum);
    k_scanB<<<1, SCAN_B, 0, stream>>>(bsum);
    k_scanC<<<SCAN_NB, SCAN_B, 0, stream>>>(off, bsum);
    k_scatter<<<(N_EDGES + 255) / 256, 256, 0, stream>>>(ei, off, deg, csr);
    k_aggr2<<<N_NODES / 4, 256, 0, stream>>>(off, csr, a_src, a_dst, xlh, y);
    k_stats<<<512, DIM, 0, stream>>>(y, bias, sums, sumsq);
    k_statfin<<<1, DIM, 0, stream>>>(sums, sumsq, gamma, beta, bias, scale, shift);
    k_final<<<(size_t)N_NODES * DIM / 4 / 256, 256, 0, stream>>>(y, x, scale, shift);
}

// Round 4
// 383.035 us; speedup vs baseline: 3.9767x; 1.1330x over previous
//
#include <hip/hip_runtime.h>
#include <hip/hip_fp16.h>
#include <math.h>

#define N_NODES 50000
#define N_EDGES 1600000
#define DIM 128
#define HEADS 8
#define NEG_SLOPE 0.2f
#define BN_EPS 1e-5f

// ---------------------------------------------------------------------------
// K1: xl = x @ W (xl stored fp16), fused per-head attention dots (fp32).
// x reads are thread-uniform -> scalar loads; W streams through L1 per lane.
// ---------------------------------------------------------------------------
#define NPB 8
__global__ void k_lin(const float* __restrict__ x, const float* __restrict__ W,
                      const float* __restrict__ att_s, const float* __restrict__ att_d,
                      __half* __restrict__ xlh, float* __restrict__ a_src,
                      float* __restrict__ a_dst) {
    const int t = threadIdx.x;              // output channel 0..127
    const int nbase = blockIdx.x * NPB;     // 50000 % 8 == 0
    float acc[NPB];
    #pragma unroll
    for (int i = 0; i < NPB; ++i) acc[i] = 0.f;
    const float* xr = x + (size_t)nbase * DIM;
    #pragma unroll 4
    for (int k = 0; k < DIM; ++k) {
        const float w = W[k * DIM + t];
        #pragma unroll
        for (int i = 0; i < NPB; ++i)
            acc[i] = fmaf(xr[i * DIM + k], w, acc[i]);   // uniform -> s_load
    }
    const float as = att_s[t];
    const float ad = att_d[t];
    #pragma unroll
    for (int i = 0; i < NPB; ++i) {
        const int n = nbase + i;
        xlh[(size_t)n * DIM + t] = __float2half(acc[i]);
        float s = acc[i] * as;
        float d = acc[i] * ad;
        #pragma unroll
        for (int off = 8; off; off >>= 1) {
            s += __shfl_xor(s, off, 16);
            d += __shfl_xor(d, off, 16);
        }
        if ((t & 15) == 0) {
            a_src[n * HEADS + (t >> 4)] = s;
            a_dst[n * HEADS + (t >> 4)] = d;
        }
    }
}

// ---------------------------------------------------------------------------
// CSR build: histogram -> exclusive scan -> two-level binned counting sort.
// ---------------------------------------------------------------------------
__global__ void k_hist(const int* __restrict__ ei, int* __restrict__ deg) {
    const int e = blockIdx.x * blockDim.x + threadIdx.x;
    if (e < N_EDGES) atomicAdd(&deg[ei[N_EDGES + e]], 1);
}

#define SCAN_B 256
#define SCAN_NB ((N_NODES + SCAN_B - 1) / SCAN_B)   // 196
#define NBUCK 196                                    // buckets of 256 nodes

__global__ void k_scanA(const int* __restrict__ deg, int* __restrict__ off,
                        int* __restrict__ bsum) {
    __shared__ int s[SCAN_B];
    const int t = threadIdx.x;
    const int i = blockIdx.x * SCAN_B + t;
    const int v = (i < N_NODES) ? deg[i] : 0;
    s[t] = v;
    __syncthreads();
    for (int d = 1; d < SCAN_B; d <<= 1) {
        const int xo = (t >= d) ? s[t - d] : 0;
        __syncthreads();
        s[t] += xo;
        __syncthreads();
    }
    if (i < N_NODES) off[i] = s[t] - v;
    if (t == SCAN_B - 1) bsum[blockIdx.x] = s[t];
}

__global__ void k_scanB(int* __restrict__ bsum) {
    __shared__ int s[SCAN_B];
    const int t = threadIdx.x;
    const int v = (t < SCAN_NB) ? bsum[t] : 0;
    s[t] = v;
    __syncthreads();
    for (int d = 1; d < SCAN_B; d <<= 1) {
        const int xo = (t >= d) ? s[t - d] : 0;
        __syncthreads();
        s[t] += xo;
        __syncthreads();
    }
    if (t < SCAN_NB) bsum[t] = s[t] - v;
}

// finalize off; also init per-bucket write cursors (bucket = node>>8)
__global__ void k_scanC(int* __restrict__ off, const int* __restrict__ bsum,
                        int* __restrict__ bcur) {
    const int t = threadIdx.x;
    const int i = blockIdx.x * SCAN_B + t;
    if (i < N_NODES) {
        const int v = off[i] + bsum[blockIdx.x];
        off[i] = v;
        if ((i & 255) == 0) bcur[i >> 8] = v;
    }
    if (i == 0) off[N_NODES] = N_EDGES;
}

// ---------------------------------------------------------------------------
// Phase A: bin edges into 196 coarse buckets (256 nodes each) with LDS
// counting sort; flush contiguous bucket segments -> coalesced writes.
// pair pack: bits[0:16)=src, [16:24)=dst&255, [24:32)=bucket.
// ---------------------------------------------------------------------------
#define CHUNK 8192
#define NB_A ((N_EDGES + CHUNK - 1) / CHUNK)   // 196

__global__ __launch_bounds__(256) void k_binA(const int* __restrict__ ei,
                                              int* __restrict__ bcur,
                                              unsigned int* __restrict__ pairs) {
    __shared__ int hist[NBUCK], excl[NBUCK], gbase[NBUCK], cnt2[NBUCK];
    __shared__ int sc[SCAN_B];
    __shared__ unsigned int buf[CHUNK];     // 32 KB
    const int t = threadIdx.x;
    const int base = blockIdx.x * CHUNK;
    const int cnt = min(CHUNK, N_EDGES - base);

    for (int j = t; j < NBUCK; j += 256) { hist[j] = 0; cnt2[j] = 0; }
    __syncthreads();
    for (int i = t; i < cnt; i += 256)
        atomicAdd(&hist[ei[N_EDGES + base + i] >> 8], 1);
    __syncthreads();
    // exclusive scan over NBUCK (padded to 256)
    sc[t] = (t < NBUCK) ? hist[t] : 0;
    __syncthreads();
    for (int d = 1; d < SCAN_B; d <<= 1) {
        const int xo = (t >= d) ? sc[t - d] : 0;
        __syncthreads();
        sc[t] += xo;
        __syncthreads();
    }
    if (t < NBUCK) {
        excl[t] = sc[t] - hist[t];
        gbase[t] = atomicAdd(&bcur[t], hist[t]);   // global segment base
    }
    __syncthreads();
    // place into LDS, sorted by bucket
    for (int i = t; i < cnt; i += 256) {
        const int s = ei[base + i];
        const int d = ei[N_EDGES + base + i];
        const int b = d >> 8;
        const int r = atomicAdd(&cnt2[b], 1);
        buf[excl[b] + r] = (unsigned int)s | ((unsigned int)(d & 255) << 16)
                         | ((unsigned int)b << 24);
    }
    __syncthreads();
    // coalesced flush of bucket segments
    for (int i = t; i < cnt; i += 256) {
        const unsigned int u = buf[i];
        const int b = u >> 24;
        pairs[gbase[b] + (i - excl[b])] = u;
    }
}

// ---------------------------------------------------------------------------
// Phase B: one block per bucket; LDS counting sort by dst&255; coalesced
// csr flush (ushort src ids). No global atomics.
// ---------------------------------------------------------------------------
#define BCAP 12288
__global__ __launch_bounds__(512) void k_binB(const unsigned int* __restrict__ pairs,
                                              const int* __restrict__ off,
                                              unsigned short* __restrict__ csr) {
    __shared__ int hist[256], excl[256], cnt2[256];
    __shared__ unsigned short out[BCAP];    // 24 KB
    const int t = threadIdx.x;
    const int b = blockIdx.x;
    const int lo = off[b << 8];
    const int nhi = min((b + 1) << 8, N_NODES);
    const int hi = off[nhi];
    const int cnt = min(hi - lo, BCAP);     // BCAP never binds (mean 8163, sd ~90)

    if (t < 256) { hist[t] = 0; cnt2[t] = 0; }
    __syncthreads();
    for (int i = t; i < cnt; i += 512)
        atomicAdd(&hist[(pairs[lo + i] >> 16) & 255], 1);
    __syncthreads();
    if (t < 256) excl[t] = hist[t];
    __syncthreads();
    for (int d = 1; d < 256; d <<= 1) {
        int xo = 0;
        if (t < 256 && t >= d) xo = excl[t - d];
        __syncthreads();
        if (t < 256) excl[t] += xo;
        __syncthreads();
    }
    if (t < 256) excl[t] -= hist[t];        // exclusive
    __syncthreads();
    for (int i = t; i < cnt; i += 512) {
        const unsigned int u = pairs[lo + i];
        const int dl = (u >> 16) & 255;
        const int r = atomicAdd(&cnt2[dl], 1);
        out[excl[dl] + r] = (unsigned short)(u & 0xFFFF);
    }
    __syncthreads();
    for (int i = t; i < cnt; i += 512)
        csr[lo + i] = out[i];
}

// ---------------------------------------------------------------------------
// K3: fused softmax + aggregation. One WAVE per dst node; lane owns 2
// adjacent channels. Edge loop unrolled x8 for MLP. No atomics, no LDS.
// ---------------------------------------------------------------------------
__global__ void k_aggr2(const int* __restrict__ off, const unsigned short* __restrict__ csr,
                        const float* __restrict__ a_src, const float* __restrict__ a_dst,
                        const __half* __restrict__ xlh, float* __restrict__ y) {
    const int d = blockIdx.x * 4 + (threadIdx.x >> 6);
    const int lane = threadIdx.x & 63;
    const int c2 = lane << 1;           // channel pair base
    const int h = lane >> 3;            // head
    const int lo = off[d], hi = off[d + 1];
    const float ad = a_dst[d * HEADS + h];
    float acc0 = 0.f, acc1 = 0.f, dsum = 0.f;
    int i = lo;
    for (; i + 8 <= hi; i += 8) {
        int s[8];
        float e[8];
        __half2 xv[8];
        #pragma unroll
        for (int j = 0; j < 8; ++j) s[j] = csr[i + j];
        #pragma unroll
        for (int j = 0; j < 8; ++j) e[j] = a_src[s[j] * HEADS + h] + ad;
        #pragma unroll
        for (int j = 0; j < 8; ++j)
            xv[j] = *(const __half2*)(xlh + (size_t)s[j] * DIM + c2);
        #pragma unroll
        for (int j = 0; j < 8; ++j) {
            const float w = __expf(fmaxf(e[j], NEG_SLOPE * e[j]));
            const float2 f = __half22float2(xv[j]);
            acc0 = fmaf(w, f.x, acc0);
            acc1 = fmaf(w, f.y, acc1);
            dsum += w;
        }
    }
    for (; i < hi; ++i) {
        const int s = csr[i];
        const float e = a_src[s * HEADS + h] + ad;
        const __half2 xv = *(const __half2*)(xlh + (size_t)s * DIM + c2);
        const float w = __expf(fmaxf(e, NEG_SLOPE * e));
        const float2 f = __half22float2(xv);
        acc0 = fmaf(w, f.x, acc0); acc1 = fmaf(w, f.y, acc1); dsum += w;
    }
    const float inv = 1.f / (dsum + 1e-16f);
    float2 o; o.x = acc0 * inv; o.y = acc1 * inv;
    *(float2*)(y + (size_t)d * DIM + c2) = o;
}

// ---------------------------------------------------------------------------
// BN stats over h = y + bias
// ---------------------------------------------------------------------------
__global__ void k_stats(const float* __restrict__ y, const float* __restrict__ bias,
                        float* __restrict__ sums, float* __restrict__ sumsq) {
    const int c = threadIdx.x;
    const float b = bias[c];
    float s = 0.f, ss = 0.f;
    for (int n = blockIdx.x; n < N_NODES; n += gridDim.x) {
        const float h = y[n * DIM + c] + b;
        s += h;
        ss += h * h;
    }
    atomicAdd(sums + c, s);
    atomicAdd(sumsq + c, ss);
}

__global__ void k_statfin(const float* __restrict__ sums, const float* __restrict__ sumsq,
                          const float* __restrict__ gamma, const float* __restrict__ beta,
                          const float* __restrict__ bias, float* __restrict__ scale,
                          float* __restrict__ shift) {
    const int c = threadIdx.x;
    const float inv_n = 1.f / (float)N_NODES;
    const float mean = sums[c] * inv_n;
    const float var = sumsq[c] * inv_n - mean * mean;
    const float sc = rsqrtf(var + BN_EPS) * gamma[c];
    scale[c] = sc;
    shift[c] = beta[c] + (bias[c] - mean) * sc;
}

// in-place float4: y = x + relu(y*scale + shift)
__global__ void k_final(float* __restrict__ y, const float* __restrict__ x,
                        const float* __restrict__ scale, const float* __restrict__ shift) {
    const int q = blockIdx.x * blockDim.x + threadIdx.x;  // float4 index
    const int cq = q & (DIM / 4 - 1);
    float4 v = ((const float4*)y)[q];
    const float4 xv = ((const float4*)x)[q];
    const float4 sc = ((const float4*)scale)[cq];
    const float4 sh = ((const float4*)shift)[cq];
    v.x = xv.x + fmaxf(v.x * sc.x + sh.x, 0.f);
    v.y = xv.y + fmaxf(v.y * sc.y + sh.y, 0.f);
    v.z = xv.z + fmaxf(v.z * sc.z + sh.z, 0.f);
    v.w = xv.w + fmaxf(v.w * sc.w + sh.w, 0.f);
    ((float4*)y)[q] = v;
}

extern "C" void kernel_launch(void* const* d_in, const int* in_sizes, int n_in,
                              void* d_out, int out_size, void* d_ws, size_t ws_size,
                              hipStream_t stream) {
    const float* x     = (const float*)d_in[0];
    const int*   ei    = (const int*)  d_in[1];   // [2,E] flat: src row then dst row
    const float* W     = (const float*)d_in[2];
    const float* att_s = (const float*)d_in[3];
    const float* att_d = (const float*)d_in[4];
    const float* bias  = (const float*)d_in[5];
    const float* gamma = (const float*)d_in[6];
    const float* beta  = (const float*)d_in[7];
    float* y = (float*)d_out;

    // workspace layout
    __half* xlh  = (__half*)d_ws;                          // 6,400,000 h (12.8 MB)
    float* a_src = (float*)(xlh + (size_t)N_NODES * DIM);  // 400,000 f
    float* a_dst = a_src + (size_t)N_NODES * HEADS;        // 400,000 f
    float* sums  = a_dst + (size_t)N_NODES * HEADS;        // 128 f
    float* sumsq = sums  + DIM;                            // 128 f
    float* scale = sumsq + DIM;                            // 128 f
    float* shift = scale + DIM;                            // 128 f
    int*   deg   = (int*)(shift + DIM);                    // 50,000 i
    int*   bsum  = deg   + N_NODES;                        // 256 i
    int*   off   = bsum  + SCAN_B;                         // 50,001 i
    int*   bcur  = off   + N_NODES + 1;                    // 200 i
    unsigned int*   pairs = (unsigned int*)(bcur + 200);   // 1,600,000 u32
    unsigned short* csr   = (unsigned short*)(pairs + N_EDGES); // 1,600,000 u16

    // zero sums/sumsq/scale/shift + deg (contiguous)
    hipMemsetAsync(sums, 0, (4 * DIM + N_NODES) * sizeof(float), stream);

    k_lin<<<N_NODES / NPB, DIM, 0, stream>>>(x, W, att_s, att_d, xlh, a_src, a_dst);
    k_hist<<<(N_EDGES + 255) / 256, 256, 0, stream>>>(ei, deg);
    k_scanA<<<SCAN_NB, SCAN_B, 0, stream>>>(deg, off, bsum);
    k_scanB<<<1, SCAN_B, 0, stream>>>(bsum);
    k_scanC<<<SCAN_NB, SCAN_B, 0, stream>>>(off, bsum, bcur);
    k_binA<<<NB_A, 256, 0, stream>>>(ei, bcur, pairs);
    k_binB<<<NBUCK, 512, 0, stream>>>(pairs, off, csr);
    k_aggr2<<<N_NODES / 4, 256, 0, stream>>>(off, csr, a_src, a_dst, xlh, y);
    k_stats<<<512, DIM, 0, stream>>>(y, bias, sums, sumsq);
    k_statfin<<<1, DIM, 0, stream>>>(sums, sumsq, gamma, beta, bias, scale, shift);
    k_final<<<(size_t)N_NODES * DIM / 4 / 256, 256, 0, stream>>>(y, x, scale, shift);
}

// Round 5
// 337.287 us; speedup vs baseline: 4.5161x; 1.1356x over previous
//
#include <hip/hip_runtime.h>
#include <hip/hip_fp16.h>
#include <math.h>

#define N_NODES 50000
#define N_EDGES 1600000
#define DIM 128
#define HEADS 8
#define NEG_SLOPE 0.2f
#define BN_EPS 1e-5f

typedef _Float16 f16x8 __attribute__((ext_vector_type(8)));
typedef float f32x4 __attribute__((ext_vector_type(4)));

// ---------------------------------------------------------------------------
// K0: swizzle W (fp32 [K=128][N=128]) into MFMA B-fragment order, fp16.
// Frag (nt,kt): lane holds B[k=kt*32+q*8+j][n=nt*16+(lane&15)], j=0..7.
// Wh[((nt*4+kt)*64+lane)*8+j]
// ---------------------------------------------------------------------------
__global__ void k_wprep(const float* __restrict__ W, __half* __restrict__ Wh) {
    const int tid = blockIdx.x * 256 + threadIdx.x;  // [0, 2048)
    const int g = tid >> 6;          // nt*4 + kt
    const int lane = tid & 63;
    const int nt = g >> 2, kt = g & 3;
    const int q = lane >> 4, n = lane & 15;
    #pragma unroll
    for (int j = 0; j < 8; ++j)
        Wh[(size_t)(g * 64 + lane) * 8 + j] =
            __float2half(W[(kt * 32 + q * 8 + j) * DIM + nt * 16 + n]);
}

// ---------------------------------------------------------------------------
// K1: xl = x @ W via MFMA 16x16x32 f16; fused per-head attention dots.
// One wave per 16 nodes (block = 4 waves = 64 nodes).
// C/D layout: col = lane&15, row = (lane>>4)*4 + reg  [m89 verified]
// A layout:   m = lane&15,   k = (lane>>4)*8 + j
// ---------------------------------------------------------------------------
__global__ __launch_bounds__(256) void k_lin(const float* __restrict__ x,
                      const __half* __restrict__ Wh, const float* __restrict__ att_s,
                      const float* __restrict__ att_d, __half* __restrict__ xlh,
                      float* __restrict__ a_src, float* __restrict__ a_dst) {
    const int wave = threadIdx.x >> 6;
    const int lane = threadIdx.x & 63;
    const int q = lane >> 4, n = lane & 15;
    const int nb = (blockIdx.x * 4 + wave) * 16;     // wave's 16-row base

    // A fragments: whole K=128 for this lane's row
    const int rowA = min(nb + n, N_NODES - 1);       // clamp (stores guarded)
    const float* xr = x + (size_t)rowA * DIM;
    f16x8 a[4];
    #pragma unroll
    for (int kt = 0; kt < 4; ++kt) {
        const float4 p0 = *(const float4*)(xr + kt * 32 + q * 8);
        const float4 p1 = *(const float4*)(xr + kt * 32 + q * 8 + 4);
        a[kt][0] = (_Float16)p0.x; a[kt][1] = (_Float16)p0.y;
        a[kt][2] = (_Float16)p0.z; a[kt][3] = (_Float16)p0.w;
        a[kt][4] = (_Float16)p1.x; a[kt][5] = (_Float16)p1.y;
        a[kt][6] = (_Float16)p1.z; a[kt][7] = (_Float16)p1.w;
    }

    f32x4 acc[8];
    #pragma unroll
    for (int nt = 0; nt < 8; ++nt) acc[nt] = (f32x4){0.f, 0.f, 0.f, 0.f};

    const f16x8* wb = (const f16x8*)Wh;
    #pragma unroll
    for (int nt = 0; nt < 8; ++nt) {
        #pragma unroll
        for (int kt = 0; kt < 4; ++kt) {
            const f16x8 b = wb[(nt * 4 + kt) * 64 + lane];
            acc[nt] = __builtin_amdgcn_mfma_f32_16x16x32_f16(a[kt], b, acc[nt], 0, 0, 0);
        }
    }

    // epilogue: store xlh (fp16) + per-head attention dots.
    // head h == n-tile nt (16 channels each). 16 lanes sharing (q,r) hold the
    // 16 channels of one row -> shuffle-reduce width 16.
    const int r0 = nb + q * 4;
    #pragma unroll
    for (int nt = 0; nt < 8; ++nt) {
        const float as = att_s[nt * 16 + n];
        const float ad = att_d[nt * 16 + n];
        #pragma unroll
        for (int r = 0; r < 4; ++r) {
            const int row = r0 + r;
            const float v = acc[nt][r];
            float s = v * as;
            float d = v * ad;
            #pragma unroll
            for (int off = 8; off; off >>= 1) {
                s += __shfl_xor(s, off, 16);
                d += __shfl_xor(d, off, 16);
            }
            if (row < N_NODES) {
                xlh[(size_t)row * DIM + nt * 16 + n] = __float2half(v);
                if (n == 0) {
                    a_src[row * HEADS + nt] = s;
                    a_dst[row * HEADS + nt] = d;
                }
            }
        }
    }
}

// ---------------------------------------------------------------------------
// CSR build: histogram -> exclusive scan -> two-level binned counting sort.
// ---------------------------------------------------------------------------
__global__ void k_hist(const int* __restrict__ ei, int* __restrict__ deg) {
    const int e4 = blockIdx.x * blockDim.x + threadIdx.x;
    if (e4 < N_EDGES / 4) {
        const int4 d = ((const int4*)(ei + N_EDGES))[e4];
        atomicAdd(&deg[d.x], 1);
        atomicAdd(&deg[d.y], 1);
        atomicAdd(&deg[d.z], 1);
        atomicAdd(&deg[d.w], 1);
    }
}

#define SCAN_B 256
#define SCAN_NB ((N_NODES + SCAN_B - 1) / SCAN_B)   // 196
#define NBUCK 196                                    // buckets of 256 nodes

__global__ void k_scanA(const int* __restrict__ deg, int* __restrict__ off,
                        int* __restrict__ bsum) {
    __shared__ int s[SCAN_B];
    const int t = threadIdx.x;
    const int i = blockIdx.x * SCAN_B + t;
    const int v = (i < N_NODES) ? deg[i] : 0;
    s[t] = v;
    __syncthreads();
    for (int d = 1; d < SCAN_B; d <<= 1) {
        const int xo = (t >= d) ? s[t - d] : 0;
        __syncthreads();
        s[t] += xo;
        __syncthreads();
    }
    if (i < N_NODES) off[i] = s[t] - v;
    if (t == SCAN_B - 1) bsum[blockIdx.x] = s[t];
}

__global__ void k_scanB(int* __restrict__ bsum) {
    __shared__ int s[SCAN_B];
    const int t = threadIdx.x;
    const int v = (t < SCAN_NB) ? bsum[t] : 0;
    s[t] = v;
    __syncthreads();
    for (int d = 1; d < SCAN_B; d <<= 1) {
        const int xo = (t >= d) ? s[t - d] : 0;
        __syncthreads();
        s[t] += xo;
        __syncthreads();
    }
    if (t < SCAN_NB) bsum[t] = s[t] - v;
}

// finalize off; also init per-bucket write cursors (bucket = node>>8)
__global__ void k_scanC(int* __restrict__ off, const int* __restrict__ bsum,
                        int* __restrict__ bcur) {
    const int t = threadIdx.x;
    const int i = blockIdx.x * SCAN_B + t;
    if (i < N_NODES) {
        const int v = off[i] + bsum[blockIdx.x];
        off[i] = v;
        if ((i & 255) == 0) bcur[i >> 8] = v;
    }
    if (i == 0) off[N_NODES] = N_EDGES;
}

// ---------------------------------------------------------------------------
// Phase A: bin edges into 196 coarse buckets (256 nodes each) with LDS
// counting sort; flush contiguous bucket segments -> coalesced writes.
// pair pack: bits[0:16)=src, [16:24)=dst&255, [24:32)=bucket.
// ---------------------------------------------------------------------------
#define CHUNK 8192
#define NB_A ((N_EDGES + CHUNK - 1) / CHUNK)   // 196

__global__ __launch_bounds__(256) void k_binA(const int* __restrict__ ei,
                                              int* __restrict__ bcur,
                                              unsigned int* __restrict__ pairs) {
    __shared__ int hist[NBUCK], excl[NBUCK], gbase[NBUCK], cnt2[NBUCK];
    __shared__ int sc[SCAN_B];
    __shared__ unsigned int buf[CHUNK];     // 32 KB
    const int t = threadIdx.x;
    const int base = blockIdx.x * CHUNK;
    const int cnt = min(CHUNK, N_EDGES - base);

    for (int j = t; j < NBUCK; j += 256) { hist[j] = 0; cnt2[j] = 0; }
    __syncthreads();
    for (int i = t; i < cnt; i += 256)
        atomicAdd(&hist[ei[N_EDGES + base + i] >> 8], 1);
    __syncthreads();
    sc[t] = (t < NBUCK) ? hist[t] : 0;
    __syncthreads();
    for (int d = 1; d < SCAN_B; d <<= 1) {
        const int xo = (t >= d) ? sc[t - d] : 0;
        __syncthreads();
        sc[t] += xo;
        __syncthreads();
    }
    if (t < NBUCK) {
        excl[t] = sc[t] - hist[t];
        gbase[t] = atomicAdd(&bcur[t], hist[t]);   // global segment base
    }
    __syncthreads();
    for (int i = t; i < cnt; i += 256) {
        const int s = ei[base + i];
        const int d = ei[N_EDGES + base + i];
        const int b = d >> 8;
        const int r = atomicAdd(&cnt2[b], 1);
        buf[excl[b] + r] = (unsigned int)s | ((unsigned int)(d & 255) << 16)
                         | ((unsigned int)b << 24);
    }
    __syncthreads();
    for (int i = t; i < cnt; i += 256) {
        const unsigned int u = buf[i];
        const int b = u >> 24;
        pairs[gbase[b] + (i - excl[b])] = u;
    }
}

// ---------------------------------------------------------------------------
// Phase B: one block per bucket; LDS counting sort by dst&255; coalesced
// csr flush (ushort src ids). No global atomics.
// ---------------------------------------------------------------------------
#define BCAP 12288
__global__ __launch_bounds__(512) void k_binB(const unsigned int* __restrict__ pairs,
                                              const int* __restrict__ off,
                                              unsigned short* __restrict__ csr) {
    __shared__ int hist[256], excl[256], cnt2[256];
    __shared__ unsigned short out[BCAP];    // 24 KB
    const int t = threadIdx.x;
    const int b = blockIdx.x;
    const int lo = off[b << 8];
    const int nhi = min((b + 1) << 8, N_NODES);
    const int hi = off[nhi];
    const int cnt = min(hi - lo, BCAP);

    if (t < 256) { hist[t] = 0; cnt2[t] = 0; }
    __syncthreads();
    for (int i = t; i < cnt; i += 512)
        atomicAdd(&hist[(pairs[lo + i] >> 16) & 255], 1);
    __syncthreads();
    if (t < 256) excl[t] = hist[t];
    __syncthreads();
    for (int d = 1; d < 256; d <<= 1) {
        int xo = 0;
        if (t < 256 && t >= d) xo = excl[t - d];
        __syncthreads();
        if (t < 256) excl[t] += xo;
        __syncthreads();
    }
    if (t < 256) excl[t] -= hist[t];
    __syncthreads();
    for (int i = t; i < cnt; i += 512) {
        const unsigned int u = pairs[lo + i];
        const int dl = (u >> 16) & 255;
        const int r = atomicAdd(&cnt2[dl], 1);
        out[excl[dl] + r] = (unsigned short)(u & 0xFFFF);
    }
    __syncthreads();
    for (int i = t; i < cnt; i += 512)
        csr[lo + i] = out[i];
}

// ---------------------------------------------------------------------------
// K3: fused softmax + aggregation. One WAVE per dst node; lane owns 2
// adjacent channels. Edge loop unrolled x8 for MLP. No atomics, no LDS.
// ---------------------------------------------------------------------------
__global__ void k_aggr2(const int* __restrict__ off, const unsigned short* __restrict__ csr,
                        const float* __restrict__ a_src, const float* __restrict__ a_dst,
                        const __half* __restrict__ xlh, float* __restrict__ y) {
    const int d = blockIdx.x * 4 + (threadIdx.x >> 6);
    const int lane = threadIdx.x & 63;
    const int c2 = lane << 1;
    const int h = lane >> 3;
    const int lo = off[d], hi = off[d + 1];
    const float ad = a_dst[d * HEADS + h];
    float acc0 = 0.f, acc1 = 0.f, dsum = 0.f;
    int i = lo;
    for (; i + 8 <= hi; i += 8) {
        int s[8];
        float e[8];
        __half2 xv[8];
        #pragma unroll
        for (int j = 0; j < 8; ++j) s[j] = csr[i + j];
        #pragma unroll
        for (int j = 0; j < 8; ++j) e[j] = a_src[s[j] * HEADS + h] + ad;
        #pragma unroll
        for (int j = 0; j < 8; ++j)
            xv[j] = *(const __half2*)(xlh + (size_t)s[j] * DIM + c2);
        #pragma unroll
        for (int j = 0; j < 8; ++j) {
            const float w = __expf(fmaxf(e[j], NEG_SLOPE * e[j]));
            const float2 f = __half22float2(xv[j]);
            acc0 = fmaf(w, f.x, acc0);
            acc1 = fmaf(w, f.y, acc1);
            dsum += w;
        }
    }
    for (; i < hi; ++i) {
        const int s = csr[i];
        const float e = a_src[s * HEADS + h] + ad;
        const __half2 xv = *(const __half2*)(xlh + (size_t)s * DIM + c2);
        const float w = __expf(fmaxf(e, NEG_SLOPE * e));
        const float2 f = __half22float2(xv);
        acc0 = fmaf(w, f.x, acc0); acc1 = fmaf(w, f.y, acc1); dsum += w;
    }
    const float inv = 1.f / (dsum + 1e-16f);
    float2 o; o.x = acc0 * inv; o.y = acc1 * inv;
    *(float2*)(y + (size_t)d * DIM + c2) = o;
}

// ---------------------------------------------------------------------------
// BN stats over h = y + bias
// ---------------------------------------------------------------------------
__global__ void k_stats(const float* __restrict__ y, const float* __restrict__ bias,
                        float* __restrict__ sums, float* __restrict__ sumsq) {
    const int c = threadIdx.x;
    const float b = bias[c];
    float s = 0.f, ss = 0.f;
    for (int n = blockIdx.x; n < N_NODES; n += gridDim.x) {
        const float h = y[n * DIM + c] + b;
        s += h;
        ss += h * h;
    }
    atomicAdd(sums + c, s);
    atomicAdd(sumsq + c, ss);
}

__global__ void k_statfin(const float* __restrict__ sums, const float* __restrict__ sumsq,
                          const float* __restrict__ gamma, const float* __restrict__ beta,
                          const float* __restrict__ bias, float* __restrict__ scale,
                          float* __restrict__ shift) {
    const int c = threadIdx.x;
    const float inv_n = 1.f / (float)N_NODES;
    const float mean = sums[c] * inv_n;
    const float var = sumsq[c] * inv_n - mean * mean;
    const float sc = rsqrtf(var + BN_EPS) * gamma[c];
    scale[c] = sc;
    shift[c] = beta[c] + (bias[c] - mean) * sc;
}

// in-place float4: y = x + relu(y*scale + shift)
__global__ void k_final(float* __restrict__ y, const float* __restrict__ x,
                        const float* __restrict__ scale, const float* __restrict__ shift) {
    const int q = blockIdx.x * blockDim.x + threadIdx.x;
    const int cq = q & (DIM / 4 - 1);
    float4 v = ((const float4*)y)[q];
    const float4 xv = ((const float4*)x)[q];
    const float4 sc = ((const float4*)scale)[cq];
    const float4 sh = ((const float4*)shift)[cq];
    v.x = xv.x + fmaxf(v.x * sc.x + sh.x, 0.f);
    v.y = xv.y + fmaxf(v.y * sc.y + sh.y, 0.f);
    v.z = xv.z + fmaxf(v.z * sc.z + sh.z, 0.f);
    v.w = xv.w + fmaxf(v.w * sc.w + sh.w, 0.f);
    ((float4*)y)[q] = v;
}

extern "C" void kernel_launch(void* const* d_in, const int* in_sizes, int n_in,
                              void* d_out, int out_size, void* d_ws, size_t ws_size,
                              hipStream_t stream) {
    const float* x     = (const float*)d_in[0];
    const int*   ei    = (const int*)  d_in[1];
    const float* W     = (const float*)d_in[2];
    const float* att_s = (const float*)d_in[3];
    const float* att_d = (const float*)d_in[4];
    const float* bias  = (const float*)d_in[5];
    const float* gamma = (const float*)d_in[6];
    const float* beta  = (const float*)d_in[7];
    float* y = (float*)d_out;

    // workspace layout
    __half* xlh  = (__half*)d_ws;                          // 6,400,000 h (12.8 MB)
    float* a_src = (float*)(xlh + (size_t)N_NODES * DIM);  // 400,000 f
    float* a_dst = a_src + (size_t)N_NODES * HEADS;        // 400,000 f
    float* sums  = a_dst + (size_t)N_NODES * HEADS;        // 128 f
    float* sumsq = sums  + DIM;                            // 128 f
    float* scale = sumsq + DIM;                            // 128 f
    float* shift = scale + DIM;                            // 128 f
    int*   deg   = (int*)(shift + DIM);                    // 50,000 i
    int*   bsum  = deg   + N_NODES;                        // 256 i
    int*   off   = bsum  + SCAN_B;                         // 50,001 i
    int*   bcur  = off   + N_NODES + 1;                    // 200 i
    unsigned int*   pairs = (unsigned int*)(bcur + 200);   // 1,600,000 u32
    unsigned short* csr   = (unsigned short*)(pairs + N_EDGES); // 1,600,000 u16
    __half* Wh   = (__half*)(csr + N_EDGES);               // 16,384 h (32 KB)

    hipMemsetAsync(sums, 0, (4 * DIM + N_NODES) * sizeof(float), stream);

    k_wprep<<<8, 256, 0, stream>>>(W, Wh);
    k_lin<<<(N_NODES + 63) / 64, 256, 0, stream>>>(x, Wh, att_s, att_d, xlh, a_src, a_dst);
    k_hist<<<(N_EDGES / 4 + 255) / 256, 256, 0, stream>>>(ei, deg);
    k_scanA<<<SCAN_NB, SCAN_B, 0, stream>>>(deg, off, bsum);
    k_scanB<<<1, SCAN_B, 0, stream>>>(bsum);
    k_scanC<<<SCAN_NB, SCAN_B, 0, stream>>>(off, bsum, bcur);
    k_binA<<<NB_A, 256, 0, stream>>>(ei, bcur, pairs);
    k_binB<<<NBUCK, 512, 0, stream>>>(pairs, off, csr);
    k_aggr2<<<N_NODES / 4, 256, 0, stream>>>(off, csr, a_src, a_dst, xlh, y);
    k_stats<<<512, DIM, 0, stream>>>(y, bias, sums, sumsq);
    k_statfin<<<1, DIM, 0, stream>>>(sums, sumsq, gamma, beta, bias, scale, shift);
    k_final<<<(size_t)N_NODES * DIM / 4 / 256, 256, 0, stream>>>(y, x, scale, shift);
}

// Round 6
// 259.258 us; speedup vs baseline: 5.8753x; 1.3010x over previous
//
#include <hip/hip_runtime.h>
#include <hip/hip_fp16.h>
#include <math.h>

#define N_NODES 50000
#define N_EDGES 1600000
#define DIM 128
#define HEADS 8
#define NEG_SLOPE 0.2f
#define BN_EPS 1e-5f

typedef _Float16 f16x8 __attribute__((ext_vector_type(8)));
typedef float f32x4 __attribute__((ext_vector_type(4)));

// ---------------------------------------------------------------------------
// K0: swizzle W (fp32 [K=128][N=128]) into MFMA B-fragment order, fp16.
// Frag (nt,kt): lane holds B[k=kt*32+q*8+j][n=nt*16+(lane&15)], j=0..7.
// ---------------------------------------------------------------------------
__global__ void k_wprep(const float* __restrict__ W, __half* __restrict__ Wh) {
    const int tid = blockIdx.x * 256 + threadIdx.x;  // [0, 2048)
    const int g = tid >> 6;          // nt*4 + kt
    const int lane = tid & 63;
    const int nt = g >> 2, kt = g & 3;
    const int q = lane >> 4, n = lane & 15;
    #pragma unroll
    for (int j = 0; j < 8; ++j)
        Wh[(size_t)(g * 64 + lane) * 8 + j] =
            __float2half(W[(kt * 32 + q * 8 + j) * DIM + nt * 16 + n]);
}

// ---------------------------------------------------------------------------
// K1: xl = x @ W via MFMA 16x16x32 f16; fused per-head attention dots.
// One wave per 16 nodes (block = 4 waves = 64 nodes).
// C/D layout: col = lane&15, row = (lane>>4)*4 + reg  [m89 verified]
// ---------------------------------------------------------------------------
__global__ __launch_bounds__(256) void k_lin(const float* __restrict__ x,
                      const __half* __restrict__ Wh, const float* __restrict__ att_s,
                      const float* __restrict__ att_d, __half* __restrict__ xlh,
                      float* __restrict__ a_src, float* __restrict__ a_dst) {
    const int wave = threadIdx.x >> 6;
    const int lane = threadIdx.x & 63;
    const int q = lane >> 4, n = lane & 15;
    const int nb = (blockIdx.x * 4 + wave) * 16;

    const int rowA = min(nb + n, N_NODES - 1);
    const float* xr = x + (size_t)rowA * DIM;
    f16x8 a[4];
    #pragma unroll
    for (int kt = 0; kt < 4; ++kt) {
        const float4 p0 = *(const float4*)(xr + kt * 32 + q * 8);
        const float4 p1 = *(const float4*)(xr + kt * 32 + q * 8 + 4);
        a[kt][0] = (_Float16)p0.x; a[kt][1] = (_Float16)p0.y;
        a[kt][2] = (_Float16)p0.z; a[kt][3] = (_Float16)p0.w;
        a[kt][4] = (_Float16)p1.x; a[kt][5] = (_Float16)p1.y;
        a[kt][6] = (_Float16)p1.z; a[kt][7] = (_Float16)p1.w;
    }

    f32x4 acc[8];
    #pragma unroll
    for (int nt = 0; nt < 8; ++nt) acc[nt] = (f32x4){0.f, 0.f, 0.f, 0.f};

    const f16x8* wb = (const f16x8*)Wh;
    #pragma unroll
    for (int nt = 0; nt < 8; ++nt) {
        #pragma unroll
        for (int kt = 0; kt < 4; ++kt) {
            const f16x8 b = wb[(nt * 4 + kt) * 64 + lane];
            acc[nt] = __builtin_amdgcn_mfma_f32_16x16x32_f16(a[kt], b, acc[nt], 0, 0, 0);
        }
    }

    const int r0 = nb + q * 4;
    #pragma unroll
    for (int nt = 0; nt < 8; ++nt) {
        const float as = att_s[nt * 16 + n];
        const float ad = att_d[nt * 16 + n];
        #pragma unroll
        for (int r = 0; r < 4; ++r) {
            const int row = r0 + r;
            const float v = acc[nt][r];
            float s = v * as;
            float d = v * ad;
            #pragma unroll
            for (int off = 8; off; off >>= 1) {
                s += __shfl_xor(s, off, 16);
                d += __shfl_xor(d, off, 16);
            }
            if (row < N_NODES) {
                xlh[(size_t)row * DIM + nt * 16 + n] = __float2half(v);
                if (n == 0) {
                    a_src[row * HEADS + nt] = s;
                    a_dst[row * HEADS + nt] = d;
                }
            }
        }
    }
}

// ---------------------------------------------------------------------------
// Binned CSR build with fixed-capacity bucket segments. No node-degree
// histogram, no global scan.
// bucket b = dst>>8 (196 buckets of <=256 nodes); segment base = b*SEGCAP.
// Bucket counts ~ Binomial(1.6M, 256/50000): mean 8192, sd 90 -> SEGCAP=12288
// is 45 sigma of headroom.
// ---------------------------------------------------------------------------
#define SCAN_B 256
#define NBUCK 196
#define SEGCAP 12288
#define CHUNK 8192
#define NB_A ((N_EDGES + CHUNK - 1) / CHUNK)   // 196

// Phase A: LDS counting sort of an 8192-edge chunk by coarse bucket; flush
// contiguous segments at cursors allocated with ONE atomic per bucket/block.
// pair pack: bits[0:16)=src, [16:24)=dst&255.
__global__ __launch_bounds__(256) void k_binA(const int* __restrict__ ei,
                                              int* __restrict__ bcur,
                                              unsigned int* __restrict__ pairs) {
    __shared__ int hist[NBUCK], excl[NBUCK], gbase[NBUCK], cnt2[NBUCK];
    __shared__ int sc[SCAN_B];
    __shared__ unsigned int buf[CHUNK];     // 32 KB
    const int t = threadIdx.x;
    const int base = blockIdx.x * CHUNK;
    const int cnt = min(CHUNK, N_EDGES - base);

    for (int j = t; j < NBUCK; j += 256) { hist[j] = 0; cnt2[j] = 0; }
    __syncthreads();
    for (int i = t; i < cnt; i += 256)
        atomicAdd(&hist[ei[N_EDGES + base + i] >> 8], 1);
    __syncthreads();
    sc[t] = (t < NBUCK) ? hist[t] : 0;
    __syncthreads();
    for (int d = 1; d < SCAN_B; d <<= 1) {
        const int xo = (t >= d) ? sc[t - d] : 0;
        __syncthreads();
        sc[t] += xo;
        __syncthreads();
    }
    if (t < NBUCK) {
        excl[t] = sc[t] - hist[t];
        gbase[t] = t * SEGCAP + atomicAdd(&bcur[t], hist[t]);
    }
    __syncthreads();
    for (int i = t; i < cnt; i += 256) {
        const int s = ei[base + i];
        const int d = ei[N_EDGES + base + i];
        const int b = d >> 8;
        const int r = atomicAdd(&cnt2[b], 1);
        buf[excl[b] + r] = (unsigned int)s | ((unsigned int)(d & 255) << 16)
                         | ((unsigned int)b << 24);
    }
    __syncthreads();
    for (int i = t; i < cnt; i += 256) {
        const unsigned int u = buf[i];
        const int b = u >> 24;
        pairs[gbase[b] + (i - excl[b])] = u & 0xFFFFFF;
    }
}

// Phase B: one block per bucket; LDS counting sort by dst&255. Emits csr
// (ushort src ids) IN-PLACE into the pairs buffer (block-private segment,
// all reads precede the staged flush) + per-node [lo,hi) ranges.
__global__ __launch_bounds__(512) void k_binB(const unsigned int* __restrict__ pairs,
                                              const int* __restrict__ bcur,
                                              unsigned short* __restrict__ csr,
                                              int2* __restrict__ nrange) {
    __shared__ int hist[256], excl[256], cnt2[256];
    __shared__ unsigned short out[SEGCAP];  // 24 KB
    const int t = threadIdx.x;
    const int b = blockIdx.x;
    const int lo = b * SEGCAP;              // u32 index into pairs
    const int cnt = bcur[b];

    if (t < 256) { hist[t] = 0; cnt2[t] = 0; }
    __syncthreads();
    for (int i = t; i < cnt; i += 512)
        atomicAdd(&hist[pairs[lo + i] >> 16], 1);
    __syncthreads();
    if (t < 256) excl[t] = hist[t];
    __syncthreads();
    for (int d = 1; d < 256; d <<= 1) {
        int xo = 0;
        if (t < 256 && t >= d) xo = excl[t - d];
        __syncthreads();
        if (t < 256) excl[t] += xo;
        __syncthreads();
    }
    if (t < 256) excl[t] -= hist[t];        // exclusive
    __syncthreads();
    for (int i = t; i < cnt; i += 512) {
        const unsigned int u = pairs[lo + i];
        const int dl = u >> 16;
        const int r = atomicAdd(&cnt2[dl], 1);
        out[excl[dl] + r] = (unsigned short)(u & 0xFFFF);
    }
    __syncthreads();
    // csr aliases pairs: u16 index base = 2*SEGCAP*b
    for (int i = t; i < cnt; i += 512)
        csr[2 * lo + i] = out[i];
    if (t < 256) {
        const int node = (b << 8) + t;
        if (node < N_NODES) {
            int2 rg;
            rg.x = 2 * lo + excl[t];
            rg.y = rg.x + hist[t];
            nrange[node] = rg;
        }
    }
}

// ---------------------------------------------------------------------------
// K3: fused softmax + aggregation. One WAVE per dst node; lane owns 2
// adjacent channels. Edge loop unrolled x8 for MLP. No atomics, no LDS.
// ---------------------------------------------------------------------------
__global__ void k_aggr2(const int2* __restrict__ nrange, const unsigned short* __restrict__ csr,
                        const float* __restrict__ a_src, const float* __restrict__ a_dst,
                        const __half* __restrict__ xlh, float* __restrict__ y) {
    const int d = blockIdx.x * 4 + (threadIdx.x >> 6);
    const int lane = threadIdx.x & 63;
    const int c2 = lane << 1;
    const int h = lane >> 3;
    const int2 rg = nrange[d];
    const int lo = rg.x, hi = rg.y;
    const float ad = a_dst[d * HEADS + h];
    float acc0 = 0.f, acc1 = 0.f, dsum = 0.f;
    int i = lo;
    for (; i + 8 <= hi; i += 8) {
        int s[8];
        float e[8];
        __half2 xv[8];
        #pragma unroll
        for (int j = 0; j < 8; ++j) s[j] = csr[i + j];
        #pragma unroll
        for (int j = 0; j < 8; ++j) e[j] = a_src[s[j] * HEADS + h] + ad;
        #pragma unroll
        for (int j = 0; j < 8; ++j)
            xv[j] = *(const __half2*)(xlh + (size_t)s[j] * DIM + c2);
        #pragma unroll
        for (int j = 0; j < 8; ++j) {
            const float w = __expf(fmaxf(e[j], NEG_SLOPE * e[j]));
            const float2 f = __half22float2(xv[j]);
            acc0 = fmaf(w, f.x, acc0);
            acc1 = fmaf(w, f.y, acc1);
            dsum += w;
        }
    }
    for (; i < hi; ++i) {
        const int s = csr[i];
        const float e = a_src[s * HEADS + h] + ad;
        const __half2 xv = *(const __half2*)(xlh + (size_t)s * DIM + c2);
        const float w = __expf(fmaxf(e, NEG_SLOPE * e));
        const float2 f = __half22float2(xv);
        acc0 = fmaf(w, f.x, acc0); acc1 = fmaf(w, f.y, acc1); dsum += w;
    }
    const float inv = 1.f / (dsum + 1e-16f);
    float2 o; o.x = acc0 * inv; o.y = acc1 * inv;
    *(float2*)(y + (size_t)d * DIM + c2) = o;
}

// ---------------------------------------------------------------------------
// BN stats over h = y + bias
// ---------------------------------------------------------------------------
__global__ void k_stats(const float* __restrict__ y, const float* __restrict__ bias,
                        float* __restrict__ sums, float* __restrict__ sumsq) {
    const int c = threadIdx.x;
    const float b = bias[c];
    float s = 0.f, ss = 0.f;
    for (int n = blockIdx.x; n < N_NODES; n += gridDim.x) {
        const float h = y[n * DIM + c] + b;
        s += h;
        ss += h * h;
    }
    atomicAdd(sums + c, s);
    atomicAdd(sumsq + c, ss);
}

__global__ void k_statfin(const float* __restrict__ sums, const float* __restrict__ sumsq,
                          const float* __restrict__ gamma, const float* __restrict__ beta,
                          const float* __restrict__ bias, float* __restrict__ scale,
                          float* __restrict__ shift) {
    const int c = threadIdx.x;
    const float inv_n = 1.f / (float)N_NODES;
    const float mean = sums[c] * inv_n;
    const float var = sumsq[c] * inv_n - mean * mean;
    const float sc = rsqrtf(var + BN_EPS) * gamma[c];
    scale[c] = sc;
    shift[c] = beta[c] + (bias[c] - mean) * sc;
}

// in-place float4: y = x + relu(y*scale + shift)
__global__ void k_final(float* __restrict__ y, const float* __restrict__ x,
                        const float* __restrict__ scale, const float* __restrict__ shift) {
    const int q = blockIdx.x * blockDim.x + threadIdx.x;
    const int cq = q & (DIM / 4 - 1);
    float4 v = ((const float4*)y)[q];
    const float4 xv = ((const float4*)x)[q];
    const float4 sc = ((const float4*)scale)[cq];
    const float4 sh = ((const float4*)shift)[cq];
    v.x = xv.x + fmaxf(v.x * sc.x + sh.x, 0.f);
    v.y = xv.y + fmaxf(v.y * sc.y + sh.y, 0.f);
    v.z = xv.z + fmaxf(v.z * sc.z + sh.z, 0.f);
    v.w = xv.w + fmaxf(v.w * sc.w + sh.w, 0.f);
    ((float4*)y)[q] = v;
}

extern "C" void kernel_launch(void* const* d_in, const int* in_sizes, int n_in,
                              void* d_out, int out_size, void* d_ws, size_t ws_size,
                              hipStream_t stream) {
    const float* x     = (const float*)d_in[0];
    const int*   ei    = (const int*)  d_in[1];
    const float* W     = (const float*)d_in[2];
    const float* att_s = (const float*)d_in[3];
    const float* att_d = (const float*)d_in[4];
    const float* bias  = (const float*)d_in[5];
    const float* gamma = (const float*)d_in[6];
    const float* beta  = (const float*)d_in[7];
    float* y = (float*)d_out;

    // workspace layout
    __half* xlh  = (__half*)d_ws;                          // 6,400,000 h (12.8 MB)
    float* a_src = (float*)(xlh + (size_t)N_NODES * DIM);  // 400,000 f
    float* a_dst = a_src + (size_t)N_NODES * HEADS;        // 400,000 f
    float* sums  = a_dst + (size_t)N_NODES * HEADS;        // 128 f
    float* sumsq = sums  + DIM;                            // 128 f
    float* scale = sumsq + DIM;                            // 128 f
    float* shift = scale + DIM;                            // 128 f
    int*   bcur  = (int*)(shift + DIM);                    // 196 i (zeroed)
    int2*  nrange = (int2*)(bcur + 256);                   // 50,000 int2
    __half* Wh   = (__half*)(nrange + N_NODES);            // 16,384 h (32 KB)
    unsigned int* pairs = (unsigned int*)(Wh + 16384);     // 196*12288 u32 (9.6 MB)
    unsigned short* csr = (unsigned short*)pairs;          // aliases pairs (in-place)

    // zero sums/sumsq/scale/shift + bcur (contiguous)
    hipMemsetAsync(sums, 0, (4 * DIM + 256) * sizeof(float), stream);

    k_wprep<<<8, 256, 0, stream>>>(W, Wh);
    k_lin<<<(N_NODES + 63) / 64, 256, 0, stream>>>(x, Wh, att_s, att_d, xlh, a_src, a_dst);
    k_binA<<<NB_A, 256, 0, stream>>>(ei, bcur, pairs);
    k_binB<<<NBUCK, 512, 0, stream>>>(pairs, bcur, csr, nrange);
    k_aggr2<<<N_NODES / 4, 256, 0, stream>>>(nrange, csr, a_src, a_dst, xlh, y);
    k_stats<<<512, DIM, 0, stream>>>(y, bias, sums, sumsq);
    k_statfin<<<1, DIM, 0, stream>>>(sums, sumsq, gamma, beta, bias, scale, shift);
    k_final<<<(size_t)N_NODES * DIM / 4 / 256, 256, 0, stream>>>(y, x, scale, shift);
}

// Round 7
// 253.922 us; speedup vs baseline: 5.9987x; 1.0210x over previous
//
#include <hip/hip_runtime.h>
#include <hip/hip_fp16.h>
#include <math.h>

#define N_NODES 50000
#define N_EDGES 1600000
#define DIM 128
#define HEADS 8
#define NEG_SLOPE 0.2f
#define BN_EPS 1e-5f

typedef _Float16 f16x8 __attribute__((ext_vector_type(8)));
typedef float f32x4 __attribute__((ext_vector_type(4)));

// ---------------------------------------------------------------------------
// K0: swizzle W (fp32 [K=128][N=128]) into MFMA B-fragment order, fp16.
// Also zero-inits bcur + BN accumulators (stream-ordered before their use).
// ---------------------------------------------------------------------------
__global__ void k_wprep(const float* __restrict__ W, __half* __restrict__ Wh,
                        int* __restrict__ bcur, float* __restrict__ gsums,
                        float* __restrict__ gsumsq) {
    const int t = threadIdx.x;
    if (blockIdx.x == 0 && t < 256) bcur[t] = 0;
    if (blockIdx.x == 1 && t < DIM) { gsums[t] = 0.f; gsumsq[t] = 0.f; }
    const int tid = blockIdx.x * 256 + t;  // [0, 2048)
    const int g = tid >> 6;          // nt*4 + kt
    const int lane = tid & 63;
    const int nt = g >> 2, kt = g & 3;
    const int q = lane >> 4, n = lane & 15;
    #pragma unroll
    for (int j = 0; j < 8; ++j)
        Wh[(size_t)(g * 64 + lane) * 8 + j] =
            __float2half(W[(kt * 32 + q * 8 + j) * DIM + nt * 16 + n]);
}

// ---------------------------------------------------------------------------
// K1: xl = x @ W via MFMA 16x16x32 f16; fused per-head attention dots.
// One wave per 16 nodes (block = 4 waves = 64 nodes).
// C/D layout: col = lane&15, row = (lane>>4)*4 + reg  [m89 verified]
// ---------------------------------------------------------------------------
__global__ __launch_bounds__(256) void k_lin(const float* __restrict__ x,
                      const __half* __restrict__ Wh, const float* __restrict__ att_s,
                      const float* __restrict__ att_d, __half* __restrict__ xlh,
                      float* __restrict__ a_src, float* __restrict__ a_dst) {
    const int wave = threadIdx.x >> 6;
    const int lane = threadIdx.x & 63;
    const int q = lane >> 4, n = lane & 15;
    const int nb = (blockIdx.x * 4 + wave) * 16;

    const int rowA = min(nb + n, N_NODES - 1);
    const float* xr = x + (size_t)rowA * DIM;
    f16x8 a[4];
    #pragma unroll
    for (int kt = 0; kt < 4; ++kt) {
        const float4 p0 = *(const float4*)(xr + kt * 32 + q * 8);
        const float4 p1 = *(const float4*)(xr + kt * 32 + q * 8 + 4);
        a[kt][0] = (_Float16)p0.x; a[kt][1] = (_Float16)p0.y;
        a[kt][2] = (_Float16)p0.z; a[kt][3] = (_Float16)p0.w;
        a[kt][4] = (_Float16)p1.x; a[kt][5] = (_Float16)p1.y;
        a[kt][6] = (_Float16)p1.z; a[kt][7] = (_Float16)p1.w;
    }

    f32x4 acc[8];
    #pragma unroll
    for (int nt = 0; nt < 8; ++nt) acc[nt] = (f32x4){0.f, 0.f, 0.f, 0.f};

    const f16x8* wb = (const f16x8*)Wh;
    #pragma unroll
    for (int nt = 0; nt < 8; ++nt) {
        #pragma unroll
        for (int kt = 0; kt < 4; ++kt) {
            const f16x8 b = wb[(nt * 4 + kt) * 64 + lane];
            acc[nt] = __builtin_amdgcn_mfma_f32_16x16x32_f16(a[kt], b, acc[nt], 0, 0, 0);
        }
    }

    const int r0 = nb + q * 4;
    #pragma unroll
    for (int nt = 0; nt < 8; ++nt) {
        const float as = att_s[nt * 16 + n];
        const float ad = att_d[nt * 16 + n];
        #pragma unroll
        for (int r = 0; r < 4; ++r) {
            const int row = r0 + r;
            const float v = acc[nt][r];
            float s = v * as;
            float d = v * ad;
            #pragma unroll
            for (int off = 8; off; off >>= 1) {
                s += __shfl_xor(s, off, 16);
                d += __shfl_xor(d, off, 16);
            }
            if (row < N_NODES) {
                xlh[(size_t)row * DIM + nt * 16 + n] = __float2half(v);
                if (n == 0) {
                    a_src[row * HEADS + nt] = s;
                    a_dst[row * HEADS + nt] = d;
                }
            }
        }
    }
}

// ---------------------------------------------------------------------------
// Binned CSR build with fixed-capacity bucket segments (no global scan).
// bucket b = dst>>8; segment base = b*SEGCAP (SEGCAP=12288, 45 sigma headroom).
// ---------------------------------------------------------------------------
#define SCAN_B 256
#define NBUCK 196
#define SEGCAP 12288
#define CHUNK 8192
#define NB_A ((N_EDGES + CHUNK - 1) / CHUNK)   // 196

// Phase A: LDS counting sort of an 8192-edge chunk by coarse bucket; flush
// contiguous segments at cursors (ONE global atomic per bucket per block).
// pair pack: bits[0:16)=src, [16:24)=dst&255, [24:32)=bucket (stripped on flush).
__global__ __launch_bounds__(256) void k_binA(const int* __restrict__ ei,
                                              int* __restrict__ bcur,
                                              unsigned int* __restrict__ pairs) {
    __shared__ int hist[NBUCK], excl[NBUCK], gbase[NBUCK], cnt2[NBUCK];
    __shared__ int sc[SCAN_B];
    __shared__ unsigned int buf[CHUNK];     // 32 KB
    const int t = threadIdx.x;
    const int base = blockIdx.x * CHUNK;
    const int cnt = min(CHUNK, N_EDGES - base);   // always multiple of 4

    for (int j = t; j < NBUCK; j += 256) { hist[j] = 0; cnt2[j] = 0; }
    __syncthreads();
    for (int i = t * 4; i < cnt; i += 1024) {
        const int4 dv = *(const int4*)(ei + N_EDGES + base + i);
        atomicAdd(&hist[dv.x >> 8], 1);
        atomicAdd(&hist[dv.y >> 8], 1);
        atomicAdd(&hist[dv.z >> 8], 1);
        atomicAdd(&hist[dv.w >> 8], 1);
    }
    __syncthreads();
    sc[t] = (t < NBUCK) ? hist[t] : 0;
    __syncthreads();
    for (int d = 1; d < SCAN_B; d <<= 1) {
        const int xo = (t >= d) ? sc[t - d] : 0;
        __syncthreads();
        sc[t] += xo;
        __syncthreads();
    }
    if (t < NBUCK) {
        excl[t] = sc[t] - hist[t];
        gbase[t] = t * SEGCAP + atomicAdd(&bcur[t], hist[t]);
    }
    __syncthreads();
    for (int i = t * 4; i < cnt; i += 1024) {
        const int4 sv = *(const int4*)(ei + base + i);
        const int4 dv = *(const int4*)(ei + N_EDGES + base + i);
        const int ss[4] = {sv.x, sv.y, sv.z, sv.w};
        const int dd[4] = {dv.x, dv.y, dv.z, dv.w};
        #pragma unroll
        for (int k = 0; k < 4; ++k) {
            const int b = dd[k] >> 8;
            const int r = atomicAdd(&cnt2[b], 1);
            buf[excl[b] + r] = (unsigned int)ss[k] | ((unsigned int)(dd[k] & 255) << 16)
                             | ((unsigned int)b << 24);
        }
    }
    __syncthreads();
    for (int i = t; i < cnt; i += 256) {
        const unsigned int u = buf[i];
        const int b = u >> 24;
        pairs[gbase[b] + (i - excl[b])] = u & 0xFFFFFF;
    }
}

// Phase B: one block per bucket; LDS counting sort by dst&255. Emits csr
// (ushort src ids) IN-PLACE into the pairs buffer + per-node [lo,hi) ranges.
__global__ __launch_bounds__(512) void k_binB(const unsigned int* __restrict__ pairs,
                                              const int* __restrict__ bcur,
                                              unsigned short* __restrict__ csr,
                                              int2* __restrict__ nrange) {
    __shared__ int hist[256], excl[256], cnt2[256];
    __shared__ unsigned short out[SEGCAP];  // 24 KB
    const int t = threadIdx.x;
    const int b = blockIdx.x;
    const int lo = b * SEGCAP;              // u32 index into pairs
    const int cnt = bcur[b];

    if (t < 256) { hist[t] = 0; cnt2[t] = 0; }
    __syncthreads();
    for (int i = t; i < cnt; i += 512)
        atomicAdd(&hist[pairs[lo + i] >> 16], 1);
    __syncthreads();
    if (t < 256) excl[t] = hist[t];
    __syncthreads();
    for (int d = 1; d < 256; d <<= 1) {
        int xo = 0;
        if (t < 256 && t >= d) xo = excl[t - d];
        __syncthreads();
        if (t < 256) excl[t] += xo;
        __syncthreads();
    }
    if (t < 256) excl[t] -= hist[t];        // exclusive
    __syncthreads();
    for (int i = t; i < cnt; i += 512) {
        const unsigned int u = pairs[lo + i];
        const int dl = u >> 16;
        const int r = atomicAdd(&cnt2[dl], 1);
        out[excl[dl] + r] = (unsigned short)(u & 0xFFFF);
    }
    __syncthreads();
    for (int i = t; i < cnt; i += 512)
        csr[2 * lo + i] = out[i];
    if (t < 256) {
        const int node = (b << 8) + t;
        if (node < N_NODES) {
            int2 rg;
            rg.x = 2 * lo + excl[t];
            rg.y = rg.x + hist[t];
            nrange[node] = rg;
        }
    }
}

// ---------------------------------------------------------------------------
// K3: fused softmax + aggregation + BN-stats accumulation.
// Wave layout: 64 lanes = 8 edge-slots x 8 heads. Each lane computes ONE
// exp per 8 edges (no redundancy); weights/src-ids broadcast via shuffles.
// Each wave processes 16 consecutive dst nodes; 16-edge masked batches.
// Per-lane BN partials -> LDS -> 256 global atomics per block.
// ---------------------------------------------------------------------------
__global__ __launch_bounds__(256) void k_aggr3(const int2* __restrict__ nrange,
                        const unsigned short* __restrict__ csr,
                        const float* __restrict__ a_src, const float* __restrict__ a_dst,
                        const __half* __restrict__ xlh, const float* __restrict__ bias,
                        float* __restrict__ y, float* __restrict__ gsums,
                        float* __restrict__ gsumsq) {
    __shared__ float ch_s[DIM], ch_ss[DIM];
    const int t = threadIdx.x;
    const int wave = t >> 6, lane = t & 63;
    const int je = lane & 7;       // edge slot
    const int h = lane >> 3;       // head (weight compute AND channel head)
    const int c2 = lane << 1;      // channel pair base
    const int wbase = lane & 56;   // first lane of this head group

    if (t < DIM) { ch_s[t] = 0.f; ch_ss[t] = 0.f; }
    __syncthreads();

    const float b0 = bias[c2], b1 = bias[c2 + 1];
    float ps0 = 0.f, pss0 = 0.f, ps1 = 0.f, pss1 = 0.f;

    const int nb = (blockIdx.x * 4 + wave) * 16;
    for (int ii = 0; ii < 16; ++ii) {
        const int d = nb + ii;
        if (d >= N_NODES) break;               // wave-uniform
        const int2 rg = nrange[d];
        const int lo = rg.x, hi = rg.y;
        const float ad = a_dst[d * HEADS + h];
        float acc0 = 0.f, acc1 = 0.f, dpart = 0.f;
        for (int i = lo; i < hi; i += 16) {
            int s0 = 0, s1 = 0;
            float w0 = 0.f, w1 = 0.f;
            if (i + je < hi) {
                s0 = csr[i + je];
                float e = a_src[s0 * HEADS + h] + ad;
                e = fmaxf(e, NEG_SLOPE * e);
                w0 = __expf(e);
            }
            if (i + 8 + je < hi) {
                s1 = csr[i + 8 + je];
                float e = a_src[s1 * HEADS + h] + ad;
                e = fmaxf(e, NEG_SLOPE * e);
                w1 = __expf(e);
            }
            dpart += w0 + w1;
            // src ids: lane j (head 0) holds edge j's src
            int sb[16];
            #pragma unroll
            for (int j = 0; j < 8; ++j) sb[j] = __shfl(s0, j);
            #pragma unroll
            for (int j = 0; j < 8; ++j) sb[8 + j] = __shfl(s1, j);
            __half2 xv[16];
            #pragma unroll
            for (int j = 0; j < 16; ++j)
                xv[j] = *(const __half2*)(xlh + (size_t)sb[j] * DIM + c2);
            #pragma unroll
            for (int j = 0; j < 8; ++j) {
                const float w = __shfl(w0, wbase | j);
                const float2 f = __half22float2(xv[j]);
                acc0 = fmaf(w, f.x, acc0); acc1 = fmaf(w, f.y, acc1);
            }
            #pragma unroll
            for (int j = 0; j < 8; ++j) {
                const float w = __shfl(w1, wbase | j);
                const float2 f = __half22float2(xv[8 + j]);
                acc0 = fmaf(w, f.x, acc0); acc1 = fmaf(w, f.y, acc1);
            }
        }
        // denominator: reduce over the 8 edge-slot lanes of this head group
        #pragma unroll
        for (int off = 1; off < 8; off <<= 1) dpart += __shfl_xor(dpart, off);
        const float inv = 1.f / (dpart + 1e-16f);
        const float o0 = acc0 * inv, o1 = acc1 * inv;
        float2 o; o.x = o0; o.y = o1;
        *(float2*)(y + (size_t)d * DIM + c2) = o;
        const float h0 = o0 + b0, h1 = o1 + b1;
        ps0 += h0; pss0 += h0 * h0;
        ps1 += h1; pss1 += h1 * h1;
    }
    atomicAdd(&ch_s[c2], ps0);      atomicAdd(&ch_s[c2 + 1], ps1);
    atomicAdd(&ch_ss[c2], pss0);    atomicAdd(&ch_ss[c2 + 1], pss1);
    __syncthreads();
    if (t < DIM) atomicAdd(&gsums[t], ch_s[t]);
    else atomicAdd(&gsumsq[t - DIM], ch_ss[t - DIM]);
}

__global__ void k_statfin(const float* __restrict__ sums, const float* __restrict__ sumsq,
                          const float* __restrict__ gamma, const float* __restrict__ beta,
                          const float* __restrict__ bias, float* __restrict__ scale,
                          float* __restrict__ shift) {
    const int c = threadIdx.x;
    const float inv_n = 1.f / (float)N_NODES;
    const float mean = sums[c] * inv_n;
    const float var = sumsq[c] * inv_n - mean * mean;
    const float sc = rsqrtf(var + BN_EPS) * gamma[c];
    scale[c] = sc;
    shift[c] = beta[c] + (bias[c] - mean) * sc;
}

// in-place float4: y = x + relu(y*scale + shift)
__global__ void k_final(float* __restrict__ y, const float* __restrict__ x,
                        const float* __restrict__ scale, const float* __restrict__ shift) {
    const int q = blockIdx.x * blockDim.x + threadIdx.x;
    const int cq = q & (DIM / 4 - 1);
    float4 v = ((const float4*)y)[q];
    const float4 xv = ((const float4*)x)[q];
    const float4 sc = ((const float4*)scale)[cq];
    const float4 sh = ((const float4*)shift)[cq];
    v.x = xv.x + fmaxf(v.x * sc.x + sh.x, 0.f);
    v.y = xv.y + fmaxf(v.y * sc.y + sh.y, 0.f);
    v.z = xv.z + fmaxf(v.z * sc.z + sh.z, 0.f);
    v.w = xv.w + fmaxf(v.w * sc.w + sh.w, 0.f);
    ((float4*)y)[q] = v;
}

extern "C" void kernel_launch(void* const* d_in, const int* in_sizes, int n_in,
                              void* d_out, int out_size, void* d_ws, size_t ws_size,
                              hipStream_t stream) {
    const float* x     = (const float*)d_in[0];
    const int*   ei    = (const int*)  d_in[1];
    const float* W     = (const float*)d_in[2];
    const float* att_s = (const float*)d_in[3];
    const float* att_d = (const float*)d_in[4];
    const float* bias  = (const float*)d_in[5];
    const float* gamma = (const float*)d_in[6];
    const float* beta  = (const float*)d_in[7];
    float* y = (float*)d_out;

    // workspace layout
    __half* xlh  = (__half*)d_ws;                          // 6,400,000 h (12.8 MB)
    float* a_src = (float*)(xlh + (size_t)N_NODES * DIM);  // 400,000 f
    float* a_dst = a_src + (size_t)N_NODES * HEADS;        // 400,000 f
    float* sums  = a_dst + (size_t)N_NODES * HEADS;        // 128 f
    float* sumsq = sums  + DIM;                            // 128 f
    float* scale = sumsq + DIM;                            // 128 f
    float* shift = scale + DIM;                            // 128 f
    int*   bcur  = (int*)(shift + DIM);                    // 256 i
    int2*  nrange = (int2*)(bcur + 256);                   // 50,000 int2
    __half* Wh   = (__half*)(nrange + N_NODES);            // 16,384 h (32 KB)
    unsigned int* pairs = (unsigned int*)(Wh + 16384);     // 196*12288 u32 (9.6 MB)
    unsigned short* csr = (unsigned short*)pairs;          // aliases pairs (in-place)

    k_wprep<<<8, 256, 0, stream>>>(W, Wh, bcur, sums, sumsq);
    k_lin<<<(N_NODES + 63) / 64, 256, 0, stream>>>(x, Wh, att_s, att_d, xlh, a_src, a_dst);
    k_binA<<<NB_A, 256, 0, stream>>>(ei, bcur, pairs);
    k_binB<<<NBUCK, 512, 0, stream>>>(pairs, bcur, csr, nrange);
    k_aggr3<<<(N_NODES + 63) / 64, 256, 0, stream>>>(nrange, csr, a_src, a_dst, xlh,
                                                     bias, y, sums, sumsq);
    k_statfin<<<1, DIM, 0, stream>>>(sums, sumsq, gamma, beta, bias, scale, shift);
    k_final<<<(size_t)N_NODES * DIM / 4 / 256, 256, 0, stream>>>(y, x, scale, shift);
}

// Round 8
// 249.514 us; speedup vs baseline: 6.1047x; 1.0177x over previous
//
#include <hip/hip_runtime.h>
#include <hip/hip_fp16.h>
#include <math.h>

#define N_NODES 50000
#define N_EDGES 1600000
#define DIM 128
#define HEADS 8
#define NEG_SLOPE 0.2f
#define BN_EPS 1e-5f

typedef _Float16 f16x8 __attribute__((ext_vector_type(8)));
typedef float f32x4 __attribute__((ext_vector_type(4)));

// ---------------------------------------------------------------------------
// K0: swizzle W (fp32 [K=128][N=128]) into MFMA B-fragment order, fp16.
// Also zero-inits bcur + BN accumulators (stream-ordered before their use).
// ---------------------------------------------------------------------------
__global__ void k_wprep(const float* __restrict__ W, __half* __restrict__ Wh,
                        int* __restrict__ bcur, float* __restrict__ gsums) {
    const int t = threadIdx.x;
    if (blockIdx.x == 0 && t < 256) bcur[t] = 0;
    if (blockIdx.x == 1 && t < 256) gsums[t] = 0.f;   // sums|sumsq contiguous
    const int tid = blockIdx.x * 256 + t;  // [0, 2048)
    const int g = tid >> 6;          // nt*4 + kt
    const int lane = tid & 63;
    const int nt = g >> 2, kt = g & 3;
    const int q = lane >> 4, n = lane & 15;
    #pragma unroll
    for (int j = 0; j < 8; ++j)
        Wh[(size_t)(g * 64 + lane) * 8 + j] =
            __float2half(W[(kt * 32 + q * 8 + j) * DIM + nt * 16 + n]);
}

// ---------------------------------------------------------------------------
// K1: xl = x @ W via MFMA 16x16x32 f16; fused per-head attention dots.
// One wave per 16 nodes (block = 4 waves = 64 nodes).
// C/D layout: col = lane&15, row = (lane>>4)*4 + reg  [m89 verified]
// ---------------------------------------------------------------------------
__global__ __launch_bounds__(256) void k_lin(const float* __restrict__ x,
                      const __half* __restrict__ Wh, const float* __restrict__ att_s,
                      const float* __restrict__ att_d, __half* __restrict__ xlh,
                      float* __restrict__ a_src, float* __restrict__ a_dst) {
    const int wave = threadIdx.x >> 6;
    const int lane = threadIdx.x & 63;
    const int q = lane >> 4, n = lane & 15;
    const int nb = (blockIdx.x * 4 + wave) * 16;

    const int rowA = min(nb + n, N_NODES - 1);
    const float* xr = x + (size_t)rowA * DIM;
    f16x8 a[4];
    #pragma unroll
    for (int kt = 0; kt < 4; ++kt) {
        const float4 p0 = *(const float4*)(xr + kt * 32 + q * 8);
        const float4 p1 = *(const float4*)(xr + kt * 32 + q * 8 + 4);
        a[kt][0] = (_Float16)p0.x; a[kt][1] = (_Float16)p0.y;
        a[kt][2] = (_Float16)p0.z; a[kt][3] = (_Float16)p0.w;
        a[kt][4] = (_Float16)p1.x; a[kt][5] = (_Float16)p1.y;
        a[kt][6] = (_Float16)p1.z; a[kt][7] = (_Float16)p1.w;
    }

    f32x4 acc[8];
    #pragma unroll
    for (int nt = 0; nt < 8; ++nt) acc[nt] = (f32x4){0.f, 0.f, 0.f, 0.f};

    const f16x8* wb = (const f16x8*)Wh;
    #pragma unroll
    for (int nt = 0; nt < 8; ++nt) {
        #pragma unroll
        for (int kt = 0; kt < 4; ++kt) {
            const f16x8 b = wb[(nt * 4 + kt) * 64 + lane];
            acc[nt] = __builtin_amdgcn_mfma_f32_16x16x32_f16(a[kt], b, acc[nt], 0, 0, 0);
        }
    }

    const int r0 = nb + q * 4;
    #pragma unroll
    for (int nt = 0; nt < 8; ++nt) {
        const float as = att_s[nt * 16 + n];
        const float ad = att_d[nt * 16 + n];
        #pragma unroll
        for (int r = 0; r < 4; ++r) {
            const int row = r0 + r;
            const float v = acc[nt][r];
            float s = v * as;
            float d = v * ad;
            #pragma unroll
            for (int off = 8; off; off >>= 1) {
                s += __shfl_xor(s, off, 16);
                d += __shfl_xor(d, off, 16);
            }
            if (row < N_NODES) {
                xlh[(size_t)row * DIM + nt * 16 + n] = __float2half(v);
                if (n == 0) {
                    a_src[row * HEADS + nt] = s;
                    a_dst[row * HEADS + nt] = d;
                }
            }
        }
    }
}

// ---------------------------------------------------------------------------
// Binned CSR build with fixed-capacity bucket segments (no global scan).
// bucket b = dst>>8; segment base = b*SEGCAP (SEGCAP=12288, 45 sigma headroom).
// ---------------------------------------------------------------------------
#define SCAN_B 256
#define NBUCK 196
#define SEGCAP 12288
#define CHUNK 8192
#define NB_A ((N_EDGES + CHUNK - 1) / CHUNK)   // 196

__global__ __launch_bounds__(256) void k_binA(const int* __restrict__ ei,
                                              int* __restrict__ bcur,
                                              unsigned int* __restrict__ pairs) {
    __shared__ int hist[NBUCK], excl[NBUCK], gbase[NBUCK], cnt2[NBUCK];
    __shared__ int sc[SCAN_B];
    __shared__ unsigned int buf[CHUNK];     // 32 KB
    const int t = threadIdx.x;
    const int base = blockIdx.x * CHUNK;
    const int cnt = min(CHUNK, N_EDGES - base);   // always multiple of 4

    for (int j = t; j < NBUCK; j += 256) { hist[j] = 0; cnt2[j] = 0; }
    __syncthreads();
    for (int i = t * 4; i < cnt; i += 1024) {
        const int4 dv = *(const int4*)(ei + N_EDGES + base + i);
        atomicAdd(&hist[dv.x >> 8], 1);
        atomicAdd(&hist[dv.y >> 8], 1);
        atomicAdd(&hist[dv.z >> 8], 1);
        atomicAdd(&hist[dv.w >> 8], 1);
    }
    __syncthreads();
    sc[t] = (t < NBUCK) ? hist[t] : 0;
    __syncthreads();
    for (int d = 1; d < SCAN_B; d <<= 1) {
        const int xo = (t >= d) ? sc[t - d] : 0;
        __syncthreads();
        sc[t] += xo;
        __syncthreads();
    }
    if (t < NBUCK) {
        excl[t] = sc[t] - hist[t];
        gbase[t] = t * SEGCAP + atomicAdd(&bcur[t], hist[t]);
    }
    __syncthreads();
    for (int i = t * 4; i < cnt; i += 1024) {
        const int4 sv = *(const int4*)(ei + base + i);
        const int4 dv = *(const int4*)(ei + N_EDGES + base + i);
        const int ss[4] = {sv.x, sv.y, sv.z, sv.w};
        const int dd[4] = {dv.x, dv.y, dv.z, dv.w};
        #pragma unroll
        for (int k = 0; k < 4; ++k) {
            const int b = dd[k] >> 8;
            const int r = atomicAdd(&cnt2[b], 1);
            buf[excl[b] + r] = (unsigned int)ss[k] | ((unsigned int)(dd[k] & 255) << 16)
                             | ((unsigned int)b << 24);
        }
    }
    __syncthreads();
    for (int i = t; i < cnt; i += 256) {
        const unsigned int u = buf[i];
        const int b = u >> 24;
        pairs[gbase[b] + (i - excl[b])] = u & 0xFFFFFF;
    }
}

__global__ __launch_bounds__(512) void k_binB(const unsigned int* __restrict__ pairs,
                                              const int* __restrict__ bcur,
                                              unsigned short* __restrict__ csr,
                                              int2* __restrict__ nrange) {
    __shared__ int hist[256], excl[256], cnt2[256];
    __shared__ unsigned short out[SEGCAP];  // 24 KB
    const int t = threadIdx.x;
    const int b = blockIdx.x;
    const int lo = b * SEGCAP;              // u32 index into pairs
    const int cnt = bcur[b];

    if (t < 256) { hist[t] = 0; cnt2[t] = 0; }
    __syncthreads();
    for (int i = t; i < cnt; i += 512)
        atomicAdd(&hist[pairs[lo + i] >> 16], 1);
    __syncthreads();
    if (t < 256) excl[t] = hist[t];
    __syncthreads();
    for (int d = 1; d < 256; d <<= 1) {
        int xo = 0;
        if (t < 256 && t >= d) xo = excl[t - d];
        __syncthreads();
        if (t < 256) excl[t] += xo;
        __syncthreads();
    }
    if (t < 256) excl[t] -= hist[t];        // exclusive
    __syncthreads();
    for (int i = t; i < cnt; i += 512) {
        const unsigned int u = pairs[lo + i];
        const int dl = u >> 16;
        const int r = atomicAdd(&cnt2[dl], 1);
        out[excl[dl] + r] = (unsigned short)(u & 0xFFFF);
    }
    __syncthreads();
    for (int i = t; i < cnt; i += 512)
        csr[2 * lo + i] = out[i];
    if (t < 256) {
        const int node = (b << 8) + t;
        if (node < N_NODES) {
            int2 rg;
            rg.x = 2 * lo + excl[t];
            rg.y = rg.x + hist[t];
            nrange[node] = rg;
        }
    }
}

// ---------------------------------------------------------------------------
// K3: fused softmax + aggregation + BN partial accumulation.
// aggr2's proven inner loop (1 node per wave-iteration, 8-edge batches,
// per-lane full dsum) at high occupancy: 1563 blocks x 4 waves, 8 nodes/wave.
// BN partials: per-lane -> LDS -> one non-atomic 256-float row per block.
// ---------------------------------------------------------------------------
#define AGG_NPW 8
#define AGG_NB  ((N_NODES + 4 * AGG_NPW - 1) / (4 * AGG_NPW))   // 1563

__global__ __launch_bounds__(256) void k_aggr4(const int2* __restrict__ nrange,
                        const unsigned short* __restrict__ csr,
                        const float* __restrict__ a_src, const float* __restrict__ a_dst,
                        const __half* __restrict__ xlh, const float* __restrict__ bias,
                        float* __restrict__ y, float* __restrict__ partials) {
    __shared__ float ch_s[DIM], ch_ss[DIM];
    const int t = threadIdx.x;
    const int wave = t >> 6, lane = t & 63;
    const int c2 = lane << 1;
    const int h = lane >> 3;
    if (t < DIM) { ch_s[t] = 0.f; ch_ss[t] = 0.f; }
    __syncthreads();

    const float b0 = bias[c2], b1 = bias[c2 + 1];
    float ps0 = 0.f, pss0 = 0.f, ps1 = 0.f, pss1 = 0.f;

    const int nb = (blockIdx.x * 4 + wave) * AGG_NPW;
    for (int ii = 0; ii < AGG_NPW; ++ii) {
        const int d = nb + ii;
        if (d >= N_NODES) break;               // wave-uniform
        const int2 rg = nrange[d];
        const int lo = rg.x, hi = rg.y;
        const float ad = a_dst[d * HEADS + h];
        float acc0 = 0.f, acc1 = 0.f, dsum = 0.f;
        int i = lo;
        for (; i + 8 <= hi; i += 8) {
            int s[8];
            float e[8];
            __half2 xv[8];
            #pragma unroll
            for (int j = 0; j < 8; ++j) s[j] = csr[i + j];
            #pragma unroll
            for (int j = 0; j < 8; ++j) e[j] = a_src[s[j] * HEADS + h] + ad;
            #pragma unroll
            for (int j = 0; j < 8; ++j)
                xv[j] = *(const __half2*)(xlh + (size_t)s[j] * DIM + c2);
            #pragma unroll
            for (int j = 0; j < 8; ++j) {
                const float w = __expf(fmaxf(e[j], NEG_SLOPE * e[j]));
                const float2 f = __half22float2(xv[j]);
                acc0 = fmaf(w, f.x, acc0);
                acc1 = fmaf(w, f.y, acc1);
                dsum += w;
            }
        }
        for (; i < hi; ++i) {
            const int s = csr[i];
            const float e = a_src[s * HEADS + h] + ad;
            const __half2 xv = *(const __half2*)(xlh + (size_t)s * DIM + c2);
            const float w = __expf(fmaxf(e, NEG_SLOPE * e));
            const float2 f = __half22float2(xv);
            acc0 = fmaf(w, f.x, acc0); acc1 = fmaf(w, f.y, acc1); dsum += w;
        }
        const float inv = 1.f / (dsum + 1e-16f);
        const float o0 = acc0 * inv, o1 = acc1 * inv;
        float2 o; o.x = o0; o.y = o1;
        *(float2*)(y + (size_t)d * DIM + c2) = o;
        const float h0 = o0 + b0, h1 = o1 + b1;
        ps0 += h0; pss0 += h0 * h0;
        ps1 += h1; pss1 += h1 * h1;
    }
    atomicAdd(&ch_s[c2], ps0);      atomicAdd(&ch_s[c2 + 1], ps1);
    atomicAdd(&ch_ss[c2], pss0);    atomicAdd(&ch_ss[c2 + 1], pss1);
    __syncthreads();
    // one non-atomic 256-float partial row per block: [sums(128) | sumsq(128)]
    partials[(size_t)blockIdx.x * 256 + t] = (t < DIM) ? ch_s[t] : ch_ss[t - DIM];
}

// reduce 1563 partial rows -> sums|sumsq (256 contiguous floats)
#define NRED 16
__global__ void k_red(const float* __restrict__ partials, float* __restrict__ gsums) {
    const int t = threadIdx.x;
    float v = 0.f;
    for (int r = blockIdx.x; r < AGG_NB; r += NRED)
        v += partials[(size_t)r * 256 + t];
    atomicAdd(&gsums[t], v);
}

__global__ void k_statfin(const float* __restrict__ sums, const float* __restrict__ sumsq,
                          const float* __restrict__ gamma, const float* __restrict__ beta,
                          const float* __restrict__ bias, float* __restrict__ scale,
                          float* __restrict__ shift) {
    const int c = threadIdx.x;
    const float inv_n = 1.f / (float)N_NODES;
    const float mean = sums[c] * inv_n;
    const float var = sumsq[c] * inv_n - mean * mean;
    const float sc = rsqrtf(var + BN_EPS) * gamma[c];
    scale[c] = sc;
    shift[c] = beta[c] + (bias[c] - mean) * sc;
}

// in-place float4: y = x + relu(y*scale + shift)
__global__ void k_final(float* __restrict__ y, const float* __restrict__ x,
                        const float* __restrict__ scale, const float* __restrict__ shift) {
    const int q = blockIdx.x * blockDim.x + threadIdx.x;
    const int cq = q & (DIM / 4 - 1);
    float4 v = ((const float4*)y)[q];
    const float4 xv = ((const float4*)x)[q];
    const float4 sc = ((const float4*)scale)[cq];
    const float4 sh = ((const float4*)shift)[cq];
    v.x = xv.x + fmaxf(v.x * sc.x + sh.x, 0.f);
    v.y = xv.y + fmaxf(v.y * sc.y + sh.y, 0.f);
    v.z = xv.z + fmaxf(v.z * sc.z + sh.z, 0.f);
    v.w = xv.w + fmaxf(v.w * sc.w + sh.w, 0.f);
    ((float4*)y)[q] = v;
}

extern "C" void kernel_launch(void* const* d_in, const int* in_sizes, int n_in,
                              void* d_out, int out_size, void* d_ws, size_t ws_size,
                              hipStream_t stream) {
    const float* x     = (const float*)d_in[0];
    const int*   ei    = (const int*)  d_in[1];
    const float* W     = (const float*)d_in[2];
    const float* att_s = (const float*)d_in[3];
    const float* att_d = (const float*)d_in[4];
    const float* bias  = (const float*)d_in[5];
    const float* gamma = (const float*)d_in[6];
    const float* beta  = (const float*)d_in[7];
    float* y = (float*)d_out;

    // workspace layout
    __half* xlh  = (__half*)d_ws;                          // 6,400,000 h (12.8 MB)
    float* a_src = (float*)(xlh + (size_t)N_NODES * DIM);  // 400,000 f
    float* a_dst = a_src + (size_t)N_NODES * HEADS;        // 400,000 f
    float* sums  = a_dst + (size_t)N_NODES * HEADS;        // 128 f
    float* sumsq = sums  + DIM;                            // 128 f
    float* scale = sumsq + DIM;                            // 128 f
    float* shift = scale + DIM;                            // 128 f
    int*   bcur  = (int*)(shift + DIM);                    // 256 i
    int2*  nrange = (int2*)(bcur + 256);                   // 50,000 int2
    __half* Wh   = (__half*)(nrange + N_NODES);            // 16,384 h (32 KB)
    unsigned int* pairs = (unsigned int*)(Wh + 16384);     // 196*12288 u32 (9.6 MB)
    unsigned short* csr = (unsigned short*)pairs;          // aliases pairs (in-place)
    float* partials = (float*)(pairs + (size_t)NBUCK * SEGCAP); // 1563*256 f (1.6 MB)

    k_wprep<<<8, 256, 0, stream>>>(W, Wh, bcur, sums);
    k_lin<<<(N_NODES + 63) / 64, 256, 0, stream>>>(x, Wh, att_s, att_d, xlh, a_src, a_dst);
    k_binA<<<NB_A, 256, 0, stream>>>(ei, bcur, pairs);
    k_binB<<<NBUCK, 512, 0, stream>>>(pairs, bcur, csr, nrange);
    k_aggr4<<<AGG_NB, 256, 0, stream>>>(nrange, csr, a_src, a_dst, xlh, bias, y, partials);
    k_red<<<NRED, 256, 0, stream>>>(partials, sums);
    k_statfin<<<1, DIM, 0, stream>>>(sums, sumsq, gamma, beta, bias, scale, shift);
    k_final<<<(size_t)N_NODES * DIM / 4 / 256, 256, 0, stream>>>(y, x, scale, shift);
}